// Round 12
// baseline (1481.644 us; speedup 1.0000x reference)
//
#include <hip/hip_runtime.h>
#include <hip/hip_bf16.h>
#include <math.h>

typedef __attribute__((ext_vector_type(4))) float f4;
typedef __attribute__((ext_vector_type(4))) float f32x4;
typedef __attribute__((ext_vector_type(8))) short s8;
typedef __attribute__((ext_vector_type(4))) short s4;

#define H 128
#define NLAYERS 3
#define FLIG 16
#define FPOC 27
#define NLIG 20000
#define NPOC 30000
#define ELIG 160000
#define EPOC 240000
#define NB 8

#define NBLK_NL ((NLIG+31)/32)   // 625
#define NBLK_NP ((NPOC+31)/32)   // 938

// packed-weight strides (elements)
#define G1S (8*8*64*8)   // K=256 GEMM1 weights per group (8 ksteps x 8 coltiles)
#define G2S (4*8*64*8)   // K=128 GEMM2 weights per group
#define W1FS (4*6*64*8)  // head W1f per f: 4 ksteps x 6 coltiles
#define WD2S (3*3*64*8)  // head Wd2: 3 ksteps x 3 coltiles

__device__ __forceinline__ float silu_f(float v){
  return v * __builtin_amdgcn_rcpf(1.0f + __expf(-v));
}
__device__ __forceinline__ unsigned short f2bf(float v){
  __hip_bfloat16 b = __float2bfloat16(v);
  return *reinterpret_cast<unsigned short*>(&b);
}
// bijective XCD-chunked swizzle
__device__ __forceinline__ int xcd_swz(int bid, int nwg){
  int q = nwg >> 3, r = nwg & 7;
  int x = bid & 7, w = bid >> 3;
  return (x < r) ? (x*(q+1) + w) : (r*(q+1) + (x-r)*q + w);
}

// ---------------- fused embedding (both graphs) + position copy ----------------
__global__ void k_embed2(const float* __restrict__ lx, const float* __restrict__ px,
                         const float* __restrict__ lpos, const float* __restrict__ ppos,
                         const float* __restrict__ Wl, const float* __restrict__ bl,
                         const float* __restrict__ Wp, const float* __restrict__ bp,
                         float* __restrict__ hl, unsigned short* __restrict__ hbl,
                         float* __restrict__ hp, unsigned short* __restrict__ hbp,
                         float* __restrict__ xl, float* __restrict__ xp){
  int bid = blockIdx.x;
  int g = (bid < NLIG/2) ? 0 : 1;
  int nb = (g ? bid - NLIG/2 : bid) * 2;
  const float* x  = g ? px : lx;
  const float* W  = g ? Wp : Wl;
  const float* b  = g ? bp : bl;
  float* h = g ? hp : hl;
  unsigned short* hb = g ? hbp : hbl;
  int F = g ? FPOC : FLIG;
  int tid = threadIdx.x;
  int n = nb + (tid >> 7);
  int j = tid & 127;
  float acc = b[j];
  for (int k = 0; k < F; k++) acc += x[n*F + k] * W[k*H + j];
  h[(size_t)n*H + j] = acc;
  hb[(size_t)n*H + j] = f2bf(acc);
  if (tid < 6){
    const float* pos = g ? ppos : lpos;
    float* xd = g ? xp : xl;
    xd[(size_t)nb*3 + tid] = pos[(size_t)nb*3 + tid];
  }
}

// ---------------- fused degree histogram ----------------
__global__ void k_hist2(const int* __restrict__ ldst, const int* __restrict__ pdst,
                        int* __restrict__ deg_l, int* __restrict__ deg_p){
  int e = blockIdx.x*256 + threadIdx.x;
  if (e < ELIG) atomicAdd(&deg_l[ldst[e]], 1);
  else if (e < ELIG+EPOC) atomicAdd(&deg_p[pdst[e-ELIG]], 1);
}

// ---------------- both exclusive scans, one dispatch ----------------
__global__ void k_scan2(const int* __restrict__ deg_l, int* __restrict__ offs_l,
                        const int* __restrict__ deg_p, int* __restrict__ offs_p){
  __shared__ int part[1024];
  const int* deg = blockIdx.x ? deg_p : deg_l;
  int* offs = blockIdx.x ? offs_p : offs_l;
  int N = blockIdx.x ? NPOC : NLIG;
  int E = blockIdx.x ? EPOC : ELIG;
  int t = threadIdx.x;
  int chunk = (N + 1023) >> 10;
  int b0 = t*chunk;
  int b1 = b0 + chunk; if (b1 > N) b1 = N;
  int s = 0;
  for (int i = b0; i < b1; i++) s += deg[i];
  part[t] = s;
  __syncthreads();
  for (int off = 1; off < 1024; off <<= 1){
    int v = (t >= off) ? part[t-off] : 0;
    __syncthreads();
    part[t] += v;
    __syncthreads();
  }
  int run = part[t] - s;
  for (int i = b0; i < b1; i++){ offs[i] = run; run += deg[i]; }
  if (t == 1023) offs[N] = E;
}

// ---------------- fused counting-sort scatter ----------------
__global__ void k_sort2(const int* __restrict__ lsrc, const int* __restrict__ ldst,
                        const int* __restrict__ psrc, const int* __restrict__ pdst,
                        const int* __restrict__ offs_l, const int* __restrict__ offs_p,
                        int* __restrict__ cur_l, int* __restrict__ cur_p,
                        int* __restrict__ ssrc_l, int* __restrict__ sdst_l,
                        int* __restrict__ ssrc_p, int* __restrict__ sdst_p){
  int e = blockIdx.x*256 + threadIdx.x;
  if (e < ELIG){
    int d = ldst[e];
    int p = offs_l[d] + atomicAdd(&cur_l[d], 1);
    ssrc_l[p] = lsrc[e]; sdst_l[p] = d;
  } else if (e < ELIG+EPOC){
    int ee = e - ELIG;
    int d = pdst[ee];
    int p = offs_p[d] + atomicAdd(&cur_p[d], 1);
    ssrc_p[p] = psrc[ee]; sdst_p[p] = d;
  }
}

// ---------------- weight packer: MFMA fragment order, fp32 -> bf16 ----------------
__global__ void k_pack(const float* __restrict__ We1, const float* __restrict__ We2,
                       const float* __restrict__ Wh1, const float* __restrict__ Wh2,
                       const float* __restrict__ Wl, const float* __restrict__ bl,
                       const float* __restrict__ Wd1, const float* __restrict__ Wd2,
                       unsigned short* __restrict__ We1p, unsigned short* __restrict__ We2p,
                       unsigned short* __restrict__ Wh1p, unsigned short* __restrict__ Wh2p,
                       unsigned short* __restrict__ W1p, unsigned short* __restrict__ Wd2p)
{
  int idx = blockIdx.x*256 + threadIdx.x;
  const int nWe1 = 6*G1S, nWe2 = 6*G2S, nWh1 = 6*G1S, nWh2 = 6*G2S, nW1 = 16*W1FS, nWd2 = WD2S;
  int i = idx;
  if (i < nWe1){
    int j = i&7, l = (i>>3)&63, t = (i>>9)&7, ks = (i>>12)&7, g = i>>15;
    int k = 32*ks + 8*(l>>4) + j, col = 16*t + (l&15);
    We1p[i] = f2bf(We1[((size_t)g*257 + k)*H + col]);
    return;
  }
  i -= nWe1;
  if (i < nWe2){
    int j = i&7, l = (i>>3)&63, t = (i>>9)&7, ks = (i>>12)&3, g = i>>14;
    int k = 32*ks + 8*(l>>4) + j, col = 16*t + (l&15);
    We2p[i] = f2bf(We2[((size_t)g*H + k)*H + col]);
    return;
  }
  i -= nWe2;
  if (i < nWh1){
    int j = i&7, l = (i>>3)&63, t = (i>>9)&7, ks = (i>>12)&7, g = i>>15;
    int k = 32*ks + 8*(l>>4) + j, col = 16*t + (l&15);
    Wh1p[i] = f2bf(Wh1[((size_t)g*256 + k)*H + col]);
    return;
  }
  i -= nWh1;
  if (i < nWh2){
    int j = i&7, l = (i>>3)&63, t = (i>>9)&7, ks = (i>>12)&3, g = i>>14;
    int k = 32*ks + 8*(l>>4) + j, col = 16*t + (l&15);
    Wh2p[i] = f2bf(Wh2[((size_t)g*H + k)*H + col]);
    return;
  }
  i -= nWh2;
  if (i < nW1){
    int f = i / W1FS, r = i % W1FS;
    int ks = r / (6*512), r2 = r % (6*512);
    int t = r2 / 512, l = (r2 % 512) >> 3, j = r2 & 7;
    int k = 32*ks + 8*(l>>4) + j, col = 16*t + (l&15);
    float v = 0.f;
    if (col < 85) v = (Wl[f*H + k] + bl[k]) * Wd1[k*85 + col];
    W1p[i] = f2bf(v);
    return;
  }
  i -= nW1;
  if (i < nWd2){
    int ks = i / (3*512), r2 = i % (3*512);
    int t = r2 / 512, l = (r2 % 512) >> 3, j = r2 & 7;
    int k = 32*ks + 8*(l>>4) + j, col = 16*t + (l&15);
    float v = 0.f;
    if (k < 85 && col < 43) v = Wd2[k*43 + col];
    Wd2p[i] = f2bf(v);
  }
}

// ---------------- FUSED LAYER: edge MLP + CSR reduce + node MLP, barrier-free ----------------
// 128 threads, 2 waves; wave owns 16 nodes + their (contiguous, dst-sorted) edges.
// Double-buffered h/hb/x: reads *_i, writes *_o (no intra-layer cross-block hazard).
__global__ __launch_bounds__(128, 2) void k_layer_f(
    const float* __restrict__ hi_l, const unsigned short* __restrict__ hbi_l,
    const float* __restrict__ xi_l,
    float* __restrict__ ho_l, unsigned short* __restrict__ hbo_l, float* __restrict__ xo_l,
    const float* __restrict__ hi_p, const unsigned short* __restrict__ hbi_p,
    const float* __restrict__ xi_p,
    float* __restrict__ ho_p, unsigned short* __restrict__ hbo_p, float* __restrict__ xo_p,
    const int* __restrict__ ssrc_l, const int* __restrict__ sdst_l,
    const int* __restrict__ ssrc_p, const int* __restrict__ sdst_p,
    const int* __restrict__ offs_l, const int* __restrict__ offs_p,
    const unsigned short* __restrict__ We1pb, const float* __restrict__ We1b,
    const float* __restrict__ be1b,
    const unsigned short* __restrict__ We2pb, const float* __restrict__ be2b,
    const float* __restrict__ Wxb, const float* __restrict__ bxb,
    const unsigned short* __restrict__ Wh1pb, const float* __restrict__ bh1b,
    const unsigned short* __restrict__ Wh2pb, const float* __restrict__ bh2b,
    int layer)
{
  __shared__ __align__(16) unsigned short m_chunk[2][128*36]; // per-wave GEMM1 out, col-major [k][slot] s=36
  __shared__ __align__(16) float aggS[2][16*132];             // per-wave fp32 agg_m, [node][col] s=132
  __shared__ float rcW[2][16][3];
  __shared__ float relW[2][32][3];
  __shared__ float d2W[2][32];
  __shared__ int dIw[2][32];   // LOCAL dst (0..15)
  __shared__ int sIw[2][32];   // global src
  __shared__ __align__(16) unsigned short u_lds[128*36];      // node u1, col-major [k][row(32)] s=36

  int tid = threadIdx.x;
  int bid = xcd_swz(blockIdx.x, NBLK_NL + NBLK_NP);
  int g = (bid < NBLK_NL) ? 0 : 1;
  int nb0 = (g ? bid - NBLK_NL : bid) * 32;
  int N = g ? NPOC : NLIG;
  const float* hi = g ? hi_p : hi_l;
  const unsigned short* hbi = g ? hbi_p : hbi_l;
  const float* xi = g ? xi_p : xi_l;
  float* ho = g ? ho_p : ho_l;
  unsigned short* hbo = g ? hbo_p : hbo_l;
  float* xo = g ? xo_p : xo_l;
  const int* ssrc = g ? ssrc_p : ssrc_l;
  const int* sdst = g ? sdst_p : sdst_l;
  const int* offs = g ? offs_p : offs_l;
  int gl = g*NLAYERS + layer;
  const unsigned short* We1p = We1pb + (size_t)gl*G1S;
  const unsigned short* We2p = We2pb + (size_t)gl*G2S;
  const float* We1r256 = We1b + ((size_t)gl*257 + 256)*H;
  const float* be1 = be1b + (size_t)gl*H;
  const float* be2 = be2b + (size_t)gl*H;
  const float* Wx = Wxb + (size_t)gl*H;
  const unsigned short* Wh1p = Wh1pb + (size_t)gl*G1S;
  const unsigned short* Wh2p = Wh2pb + (size_t)gl*G2S;
  const float* bh1 = bh1b + (size_t)gl*H;
  const float* bh2 = bh2b + (size_t)gl*H;

  int lane = tid & 63, wv = tid >> 6;
  int c = lane & 15, q = lane >> 4;

  // zero wave-private accumulators
  for (int i = lane; i < 16*132; i += 64) aggS[wv][i] = 0.f;
  if (lane < 48) rcW[wv][lane/3][lane - (lane/3)*3] = 0.f;

  int gn0 = nb0 + wv*16;
  int lo = gn0 < N ? gn0 : N;
  int hi2 = gn0+16 < N ? gn0+16 : N;
  int oa = offs[lo], ob = offs[hi2];
  float bxv = bxb[gl];

  // ---- edge chunks of 32 (2 tiles of 16) ----
  for (int eb = oa; eb < ob; eb += 32){
    if (lane < 32){
      int eg = eb + lane;
      int egc = eg < ob ? eg : ob-1;
      int s = ssrc[egc], d = sdst[egc];
      sIw[wv][lane] = s;
      dIw[wv][lane] = d - gn0;
      float rx = xi[d*3+0]-xi[s*3+0];
      float ry = xi[d*3+1]-xi[s*3+1];
      float rz = xi[d*3+2]-xi[s*3+2];
      relW[wv][lane][0]=rx; relW[wv][lane][1]=ry; relW[wv][lane][2]=rz;
      d2W[wv][lane] = rx*rx+ry*ry+rz*rz;
    }
    // A-frags for this lane's two tile rows (slots c and 16+c)
    int dg0 = gn0 + dIw[wv][c],    sg0 = sIw[wv][c];
    int dg1 = gn0 + dIw[wv][16+c], sg1 = sIw[wv][16+c];
    const unsigned short* pD0 = hbi + (size_t)dg0*H + q*8;
    const unsigned short* pS0 = hbi + (size_t)sg0*H + q*8;
    const unsigned short* pD1 = hbi + (size_t)dg1*H + q*8;
    const unsigned short* pS1 = hbi + (size_t)sg1*H + q*8;
    s8 af0[8], af1[8];
    #pragma unroll
    for (int ks=0; ks<4; ks++){
      af0[ks]   = *(const s8*)(pD0 + ks*32);
      af0[4+ks] = *(const s8*)(pS0 + ks*32);
      af1[ks]   = *(const s8*)(pD1 + ks*32);
      af1[4+ks] = *(const s8*)(pS1 + ks*32);
    }

    // GEMM1 (K=256), B shared across tiles
    f32x4 acc0[8], acc1[8];
    #pragma unroll
    for (int t=0;t<8;t++){ acc0[t] = (f32x4){0.f,0.f,0.f,0.f}; acc1[t] = (f32x4){0.f,0.f,0.f,0.f}; }
    const s8* B1 = (const s8*)We1p;
    #pragma unroll
    for (int ks=0; ks<8; ks++){
      const s8* bp = B1 + (ks*8)*64 + lane;
      #pragma unroll
      for (int t=0;t<8;t++){
        s8 B = bp[t*64];
        acc0[t] = __builtin_amdgcn_mfma_f32_16x16x32_bf16(af0[ks], B, acc0[t], 0,0,0);
        acc1[t] = __builtin_amdgcn_mfma_f32_16x16x32_bf16(af1[ks], B, acc1[t], 0,0,0);
      }
    }

    int er0 = 4*q, er1 = 16 + 4*q;
    float d20[4], d21[4];
    #pragma unroll
    for (int i=0;i<4;i++){ d20[i] = d2W[wv][er0+i]; d21[i] = d2W[wv][er1+i]; }
    unsigned short* mw = &m_chunk[wv][0];
    #pragma unroll
    for (int t=0;t<8;t++){
      int j2 = 16*t + c;
      float w256 = We1r256[j2], bias = be1[j2];
      s4 mv0, mv1;
      #pragma unroll
      for (int i=0;i<4;i++){
        mv0[i] = (short)f2bf(silu_f(acc0[t][i] + d20[i]*w256 + bias));
        mv1[i] = (short)f2bf(silu_f(acc1[t][i] + d21[i]*w256 + bias));
      }
      *(s4*)&mw[36*j2 + er0] = mv0;
      *(s4*)&mw[36*j2 + er1] = mv1;
    }

    // GEMM2 (K=128), wave-private m_chunk reads
    #pragma unroll
    for (int t=0;t<8;t++){ acc0[t] = (f32x4){0.f,0.f,0.f,0.f}; acc1[t] = (f32x4){0.f,0.f,0.f,0.f}; }
    const s8* B2 = (const s8*)We2p;
    #pragma unroll
    for (int ks=0; ks<4; ks++){
      s8 a20, a21;
      int base = 36*(32*ks + 8*q) + c;
      #pragma unroll
      for (int j=0;j<8;j++){
        a20[j] = (short)mw[base + 36*j];
        a21[j] = (short)mw[base + 16 + 36*j];
      }
      const s8* bp = B2 + (ks*8)*64 + lane;
      #pragma unroll
      for (int t=0;t<8;t++){
        s8 B = bp[t*64];
        acc0[t] = __builtin_amdgcn_mfma_f32_16x16x32_bf16(a20, B, acc0[t], 0,0,0);
        acc1[t] = __builtin_amdgcn_mfma_f32_16x16x32_bf16(a21, B, acc1[t], 0,0,0);
      }
    }

    // epilogue: silu + validity-masked segmented LDS-atomic reduce + coef partials
    int dl0[4], dl1[4];
    float vm0[4], vm1[4];
    #pragma unroll
    for (int i=0;i<4;i++){
      dl0[i] = dIw[wv][er0+i];
      dl1[i] = dIw[wv][er1+i];
      vm0[i] = (eb + er0 + i < ob) ? 1.f : 0.f;
      vm1[i] = (eb + er1 + i < ob) ? 1.f : 0.f;
    }
    float pp0[4] = {0.f,0.f,0.f,0.f};
    float pp1[4] = {0.f,0.f,0.f,0.f};
    float* ag = &aggS[wv][0];
    #pragma unroll
    for (int t=0;t<8;t++){
      int j2 = 16*t + c;
      float b2v = be2[j2], wxv = Wx[j2];
      float v0[4], v1[4];
      #pragma unroll
      for (int i=0;i<4;i++){
        v0[i] = silu_f(acc0[t][i] + b2v);
        v1[i] = silu_f(acc1[t][i] + b2v);
        pp0[i] += v0[i]*wxv;
        pp1[i] += v1[i]*wxv;
      }
      // tile0 merge
      float s = v0[0]*vm0[0];
      if (dl0[1]!=dl0[0]){ atomicAdd(&ag[dl0[0]*132 + j2], s); s = v0[1]*vm0[1]; } else s += v0[1]*vm0[1];
      if (dl0[2]!=dl0[1]){ atomicAdd(&ag[dl0[1]*132 + j2], s); s = v0[2]*vm0[2]; } else s += v0[2]*vm0[2];
      if (dl0[3]!=dl0[2]){ atomicAdd(&ag[dl0[2]*132 + j2], s); s = v0[3]*vm0[3]; } else s += v0[3]*vm0[3];
      atomicAdd(&ag[dl0[3]*132 + j2], s);
      // tile1 merge
      s = v1[0]*vm1[0];
      if (dl1[1]!=dl1[0]){ atomicAdd(&ag[dl1[0]*132 + j2], s); s = v1[1]*vm1[1]; } else s += v1[1]*vm1[1];
      if (dl1[2]!=dl1[1]){ atomicAdd(&ag[dl1[1]*132 + j2], s); s = v1[2]*vm1[2]; } else s += v1[2]*vm1[2];
      if (dl1[3]!=dl1[2]){ atomicAdd(&ag[dl1[2]*132 + j2], s); s = v1[3]*vm1[3]; } else s += v1[3]*vm1[3];
      atomicAdd(&ag[dl1[3]*132 + j2], s);
    }
    #pragma unroll
    for (int off=1; off<16; off<<=1){
      #pragma unroll
      for (int i=0;i<4;i++){
        pp0[i] += __shfl_xor(pp0[i], off, 64);
        pp1[i] += __shfl_xor(pp1[i], off, 64);
      }
    }
    if (c == 0){
      #pragma unroll
      for (int i=0;i<4;i++){
        int sl = er0 + i;
        if (eb + sl < ob){
          int dl = dIw[wv][sl];
          float cf = pp0[i] + bxv;
          atomicAdd(&rcW[wv][dl][0], relW[wv][sl][0]*cf);
          atomicAdd(&rcW[wv][dl][1], relW[wv][sl][1]*cf);
          atomicAdd(&rcW[wv][dl][2], relW[wv][sl][2]*cf);
        }
        sl = er1 + i;
        if (eb + sl < ob){
          int dl = dIw[wv][sl];
          float cf = pp1[i] + bxv;
          atomicAdd(&rcW[wv][dl][0], relW[wv][sl][0]*cf);
          atomicAdd(&rcW[wv][dl][1], relW[wv][sl][1]*cf);
          atomicAdd(&rcW[wv][dl][2], relW[wv][sl][2]*cf);
        }
      }
    }
  } // chunk loop

  // ---- x update (wave-private) ----
  if (lane < 48){
    int nl = lane/3, cc = lane - nl*3;
    int gn = gn0 + nl;
    if (gn < N){
      int dvi = offs[gn+1] - offs[gn];
      float dv = dvi < 1 ? 1.f : (float)dvi;
      xo[(size_t)gn*3 + cc] = xi[(size_t)gn*3 + cc] + rcW[wv][nl][cc]*__builtin_amdgcn_rcpf(dv);
    }
  }

  // ---- node MLP phase (wave owns its 16 nodes) ----
  int node = gn0 + c;
  int na = node < N ? node : N-1;

  s8 af[8];
  #pragma unroll
  for (int ks=0; ks<4; ks++)
    af[ks] = *(const s8*)(hbi + (size_t)na*H + ks*32 + q*8);
  #pragma unroll
  for (int ks=4; ks<8; ks++){
    const float* am = &aggS[wv][c*132 + (ks-4)*32 + q*8];
    f4 a0 = *(const f4*)am, a1 = *(const f4*)(am+4);
    s8 p;
    #pragma unroll
    for (int jj=0;jj<4;jj++){ p[jj] = (short)f2bf(a0[jj]); p[4+jj] = (short)f2bf(a1[jj]); }
    af[ks] = p;
  }

  f32x4 acc[8];
  #pragma unroll
  for (int t=0;t<8;t++) acc[t] = (f32x4){0.f,0.f,0.f,0.f};
  const s8* B1n = (const s8*)Wh1p;
  #pragma unroll
  for (int ks=0; ks<8; ks++){
    const s8* bp = B1n + (ks*8)*64 + lane;
    #pragma unroll
    for (int t=0;t<8;t++)
      acc[t] = __builtin_amdgcn_mfma_f32_16x16x32_bf16(af[ks], bp[t*64], acc[t], 0,0,0);
  }

  int nr0 = wv*16 + 4*q;
  #pragma unroll
  for (int t=0;t<8;t++){
    int j2 = 16*t + c;
    float b1 = bh1[j2];
    s4 mv;
    #pragma unroll
    for (int i=0;i<4;i++) mv[i] = (short)f2bf(silu_f(acc[t][i] + b1));
    *(s4*)&u_lds[36*j2 + nr0] = mv;   // wave-private rows
  }

  f32x4 acc2[8];
  #pragma unroll
  for (int t=0;t<8;t++) acc2[t] = (f32x4){0.f,0.f,0.f,0.f};
  const s8* B2n = (const s8*)Wh2p;
  #pragma unroll
  for (int ks=0; ks<4; ks++){
    s8 a2;
    int base = 36*(32*ks + 8*q) + wv*16 + c;
    #pragma unroll
    for (int j=0;j<8;j++) a2[j] = (short)u_lds[base + 36*j];
    const s8* bp = B2n + (ks*8)*64 + lane;
    #pragma unroll
    for (int t=0;t<8;t++)
      acc2[t] = __builtin_amdgcn_mfma_f32_16x16x32_bf16(a2, bp[t*64], acc2[t], 0,0,0);
  }

  #pragma unroll
  for (int t=0;t<8;t++){
    int j2 = 16*t + c;
    float b2 = bh2[j2];
    #pragma unroll
    for (int i=0;i<4;i++){
      int gr = gn0 + 4*q + i;
      if (gr < N){
        size_t off = (size_t)gr*H + j2;
        float hv = hi[off] + acc2[t][i] + b2;
        ho[off] = hv;
        hbo[off] = f2bf(hv);
      }
    }
  }
}

// ---------------- NextType head via bf16 MFMA, 8 waves, f-parallel ----------------
__global__ __launch_bounds__(512, 2) void k_head3(
    const unsigned short* __restrict__ hb, const int* __restrict__ batch,
    const unsigned short* __restrict__ W1p, const float* __restrict__ bd1,
    const unsigned short* __restrict__ Wd2p, const float* __restrict__ bd2,
    const float* __restrict__ Wd3, const float* __restrict__ bd3,
    float* __restrict__ agg, int N)
{
  __shared__ __align__(16) unsigned short t1tr[96*132];
  __shared__ float t3s[32][18];
  __shared__ float lgs[32][18];
  __shared__ int bI[32];

  int tid = threadIdx.x;
  int nb0 = blockIdx.x * 32;
  int lane = tid & 63, wave = tid >> 6;
  int pair = wave >> 1, sub = wave & 1;
  int c = lane & 15, q = lane >> 4;

  int node = nb0 + sub*16 + c;
  int na = node < N ? node : N-1;

  s8 ah[4];
  #pragma unroll
  for (int ks=0; ks<4; ks++)
    ah[ks] = *(const s8*)(hb + (size_t)na*H + ks*32 + q*8);

  float b1c[6];
  #pragma unroll
  for (int t=0;t<6;t++){ int col=16*t+c; b1c[t] = (col<85) ? bd1[col] : 0.f; }
  float b2c[3], w3c[3];
  #pragma unroll
  for (int t=0;t<3;t++){
    int col=16*t+c;
    b2c[t] = (col<43) ? bd2[col] : 0.f;
    w3c[t] = (col<43) ? Wd3[col] : 0.f;
  }
  float bd3v = bd3[0];
  int rbase = wave*16;
  int er0 = rbase + 4*q;

  for (int fi=0; fi<4; fi++){
    int f = pair + 4*fi;
    const s8* B1 = (const s8*)W1p + f*(W1FS/8);
    f32x4 acc[6];
    #pragma unroll
    for (int t=0;t<6;t++) acc[t] = (f32x4){0.f,0.f,0.f,0.f};
    #pragma unroll
    for (int ks=0; ks<4; ks++){
      #pragma unroll
      for (int t=0;t<6;t++)
        acc[t] = __builtin_amdgcn_mfma_f32_16x16x32_bf16(ah[ks], B1[(ks*6+t)*64+lane], acc[t], 0,0,0);
    }
    #pragma unroll
    for (int t=0;t<6;t++){
      int j2 = 16*t + c;
      s4 mv;
      #pragma unroll
      for (int i=0;i<4;i++) mv[i] = (short)f2bf(silu_f(acc[t][i] + b1c[t]));
      *(s4*)&t1tr[132*j2 + er0] = mv;
    }
    f32x4 acc2[3];
    #pragma unroll
    for (int t=0;t<3;t++) acc2[t] = (f32x4){0.f,0.f,0.f,0.f};
    const s8* B2 = (const s8*)Wd2p;
    #pragma unroll
    for (int ks=0; ks<3; ks++){
      s8 a2;
      int base = 132*(32*ks + 8*q) + rbase + c;
      #pragma unroll
      for (int j=0;j<8;j++) a2[j] = (short)t1tr[base + 132*j];
      #pragma unroll
      for (int t=0;t<3;t++)
        acc2[t] = __builtin_amdgcn_mfma_f32_16x16x32_bf16(a2, B2[(ks*3+t)*64+lane], acc2[t], 0,0,0);
    }
    float pp[4] = {0.f,0.f,0.f,0.f};
    #pragma unroll
    for (int t=0;t<3;t++){
      #pragma unroll
      for (int i=0;i<4;i++) pp[i] += silu_f(acc2[t][i] + b2c[t]) * w3c[t];
    }
    #pragma unroll
    for (int off=1; off<16; off<<=1){
      #pragma unroll
      for (int i=0;i<4;i++) pp[i] += __shfl_xor(pp[i], off, 64);
    }
    if (c == 0){
      #pragma unroll
      for (int i=0;i<4;i++) t3s[sub*16 + 4*q + i][f] = pp[i] + bd3v;
    }
  }
  __syncthreads();

  if (tid < 32){
    int n = nb0 + tid;
    bool valid = n < N;
    bI[tid] = batch[valid ? n : (N-1)];
    if (valid){
      float m = t3s[tid][0];
      #pragma unroll
      for (int i=1;i<16;i++) m = fmaxf(m, t3s[tid][i]);
      float s = 0.f;
      #pragma unroll
      for (int i=0;i<16;i++) s += __expf(t3s[tid][i] - m);
      float ls = __logf(s);
      #pragma unroll
      for (int i=0;i<16;i++) lgs[tid][i] = t3s[tid][i] - m - ls;
    } else {
      #pragma unroll
      for (int i=0;i<16;i++) lgs[tid][i] = 0.f;
    }
  }
  __syncthreads();

  if (tid < 16){
    int f = tid;
    float acc = 0.f; int run = bI[0];
    for (int n = 0; n < 32; n++){
      int b = bI[n];
      if (b != run){ atomicAdd(&agg[run*16 + f], acc); acc = 0.f; run = b; }
      acc += lgs[n][f];
    }
    atomicAdd(&agg[run*16 + f], acc);
  }
}

// ---------------- final: out = agg - logsumexp(agg) ----------------
__global__ void k_final(const float* __restrict__ agg, float* __restrict__ out){
  int tid = threadIdx.x;
  float vv = agg[tid];
  float m = vv;
  #pragma unroll
  for (int off = 1; off < 16; off <<= 1) m = fmaxf(m, __shfl_xor(m, off, 64));
  float s = __expf(vv - m);
  #pragma unroll
  for (int off = 1; off < 16; off <<= 1) s += __shfl_xor(s, off, 64);
  out[tid] = vv - m - __logf(s);
}

extern "C" void kernel_launch(void* const* d_in, const int* in_sizes, int n_in,
                              void* d_out, int out_size, void* d_ws, size_t ws_size,
                              hipStream_t stream)
{
  const float* ligand_x   = (const float*)d_in[0];
  const float* pocket_x   = (const float*)d_in[1];
  const float* ligand_pos = (const float*)d_in[2];
  const float* pocket_pos = (const float*)d_in[3];
  const float* Wl_emb = (const float*)d_in[4];
  const float* bl_emb = (const float*)d_in[5];
  const float* Wp_emb = (const float*)d_in[6];
  const float* bp_emb = (const float*)d_in[7];
  const float* We1 = (const float*)d_in[8];
  const float* be1 = (const float*)d_in[9];
  const float* We2 = (const float*)d_in[10];
  const float* be2 = (const float*)d_in[11];
  const float* Wx  = (const float*)d_in[12];
  const float* bx  = (const float*)d_in[13];
  const float* Wh1 = (const float*)d_in[14];
  const float* bh1 = (const float*)d_in[15];
  const float* Wh2 = (const float*)d_in[16];
  const float* bh2 = (const float*)d_in[17];
  const float* Wd1 = (const float*)d_in[18];
  const float* bd1 = (const float*)d_in[19];
  const float* Wd2 = (const float*)d_in[20];
  const float* bd2 = (const float*)d_in[21];
  const float* Wd3 = (const float*)d_in[22];
  const float* bd3 = (const float*)d_in[23];
  const int* l2l    = (const int*)d_in[24];
  const int* p2p    = (const int*)d_in[25];
  const int* lbatch = (const int*)d_in[26];

  char* w = (char*)d_ws;
  auto alloc = [&](size_t bytes)->char*{
    char* p = w; w += (bytes + 255) & ~(size_t)255; return p;
  };
  float* hA_l = (float*)alloc((size_t)NLIG*H*4);
  float* hB_l = (float*)alloc((size_t)NLIG*H*4);
  float* hA_p = (float*)alloc((size_t)NPOC*H*4);
  float* hB_p = (float*)alloc((size_t)NPOC*H*4);
  unsigned short* hbA_l = (unsigned short*)alloc((size_t)NLIG*H*2);
  unsigned short* hbB_l = (unsigned short*)alloc((size_t)NLIG*H*2);
  unsigned short* hbA_p = (unsigned short*)alloc((size_t)NPOC*H*2);
  unsigned short* hbB_p = (unsigned short*)alloc((size_t)NPOC*H*2);
  float* xA_l = (float*)alloc((size_t)NLIG*3*4);
  float* xB_l = (float*)alloc((size_t)NLIG*3*4);
  float* xA_p = (float*)alloc((size_t)NPOC*3*4);
  float* xB_p = (float*)alloc((size_t)NPOC*3*4);
  int* offs_l = (int*)alloc((size_t)(NLIG+1)*4);
  int* offs_p = (int*)alloc((size_t)(NPOC+1)*4);
  int* ssrc_l = (int*)alloc((size_t)ELIG*4);
  int* sdst_l = (int*)alloc((size_t)ELIG*4);
  int* ssrc_p = (int*)alloc((size_t)EPOC*4);
  int* sdst_p = (int*)alloc((size_t)EPOC*4);
  unsigned short* We1p = (unsigned short*)alloc((size_t)6*G1S*2);
  unsigned short* We2p = (unsigned short*)alloc((size_t)6*G2S*2);
  unsigned short* Wh1p = (unsigned short*)alloc((size_t)6*G1S*2);
  unsigned short* Wh2p = (unsigned short*)alloc((size_t)6*G2S*2);
  unsigned short* W1p  = (unsigned short*)alloc((size_t)16*W1FS*2);
  unsigned short* Wd2p = (unsigned short*)alloc((size_t)WD2S*2);
  // ---- contiguous zero-init region ----
  char* zbase = w;
  int* deg_l = (int*)alloc((size_t)NLIG*4);
  int* deg_p = (int*)alloc((size_t)NPOC*4);
  int* cur_l = (int*)alloc((size_t)NLIG*4);
  int* cur_p = (int*)alloc((size_t)NPOC*4);
  float* aggB = (float*)alloc((size_t)NB*16*4);
  size_t zsize = (size_t)(w - zbase);

  hipMemsetAsync(zbase, 0, zsize, stream);

  const int* lsrc = l2l;          const int* ldst = l2l + ELIG;
  const int* psrc = p2p;          const int* pdst = p2p + EPOC;

  k_embed2<<<NLIG/2 + NPOC/2, 256, 0, stream>>>(ligand_x, pocket_x, ligand_pos, pocket_pos,
      Wl_emb, bl_emb, Wp_emb, bp_emb, hA_l, hbA_l, hA_p, hbA_p, xA_l, xA_p);
  k_hist2<<<(ELIG+EPOC+255)/256, 256, 0, stream>>>(ldst, pdst, deg_l, deg_p);
  k_scan2<<<2, 1024, 0, stream>>>(deg_l, offs_l, deg_p, offs_p);
  k_sort2<<<(ELIG+EPOC+255)/256, 256, 0, stream>>>(lsrc, ldst, psrc, pdst,
      offs_l, offs_p, cur_l, cur_p, ssrc_l, sdst_l, ssrc_p, sdst_p);
  {
    int npack = 6*G1S + 6*G2S + 6*G1S + 6*G2S + 16*W1FS + WD2S;
    k_pack<<<(npack+255)/256, 256, 0, stream>>>(We1, We2, Wh1, Wh2,
        Wl_emb, bl_emb, Wd1, Wd2, We1p, We2p, Wh1p, Wh2p, W1p, Wd2p);
  }

  for (int l = 0; l < NLAYERS; l++){
    bool odd = (l & 1);
    const float* hi_l = odd ? hB_l : hA_l;        float* ho_l = odd ? hA_l : hB_l;
    const float* hi_p = odd ? hB_p : hA_p;        float* ho_p = odd ? hA_p : hB_p;
    const unsigned short* hbi_l = odd ? hbB_l : hbA_l;
    unsigned short* hbo_l = odd ? hbA_l : hbB_l;
    const unsigned short* hbi_p = odd ? hbB_p : hbA_p;
    unsigned short* hbo_p = odd ? hbA_p : hbB_p;
    const float* xi_l = odd ? xB_l : xA_l;        float* xo_l = odd ? xA_l : xB_l;
    const float* xi_p = odd ? xB_p : xA_p;        float* xo_p = odd ? xA_p : xB_p;
    k_layer_f<<<NBLK_NL + NBLK_NP, 128, 0, stream>>>(
        hi_l, hbi_l, xi_l, ho_l, hbo_l, xo_l,
        hi_p, hbi_p, xi_p, ho_p, hbo_p, xo_p,
        ssrc_l, sdst_l, ssrc_p, sdst_p, offs_l, offs_p,
        We1p, We1, be1, We2p, be2, Wx, bx,
        Wh1p, bh1, Wh2p, bh2, l);
  }

  // 3 layers: final output buffers are the "B" set (A->B, B->A, A->B)
  k_head3<<<(NLIG+31)/32, 512, 0, stream>>>(hbB_l, lbatch, W1p, bd1, Wd2p, bd2,
                                            Wd3, bd3, aggB, NLIG);
  k_final<<<1, 128, 0, stream>>>(aggB, (float*)d_out);
}

// Round 13
// 796.635 us; speedup vs baseline: 1.8599x; 1.8599x over previous
//
#include <hip/hip_runtime.h>
#include <hip/hip_bf16.h>
#include <math.h>

typedef __attribute__((ext_vector_type(4))) float f4;
typedef __attribute__((ext_vector_type(4))) float f32x4;
typedef __attribute__((ext_vector_type(8))) short s8;
typedef __attribute__((ext_vector_type(4))) short s4;

#define H 128
#define NLAYERS 3
#define FLIG 16
#define FPOC 27
#define NLIG 20000
#define NPOC 30000
#define ELIG 160000
#define EPOC 240000
#define NB 8

#define EPB 128                  // edges per block
#define NBLK_EL (ELIG/EPB)       // 1250
#define NBLK_EP (EPOC/EPB)       // 1875
#define NBLK_NL ((NLIG+31)/32)   // 625
#define NBLK_NP ((NPOC+31)/32)   // 938

// packed-weight strides (elements)
#define G1S (8*8*64*8)   // K=256 GEMM1 weights per group (8 ksteps x 8 coltiles)
#define G2S (4*8*64*8)   // K=128 GEMM2 weights per group
#define W1FS (4*6*64*8)  // head W1f per f: 4 ksteps x 6 coltiles
#define WD2S (3*3*64*8)  // head Wd2: 3 ksteps x 3 coltiles

// silu with hw rcp (rel err ~1e-5, far below bf16 eps)
__device__ __forceinline__ float silu_f(float v){
  return v * __builtin_amdgcn_rcpf(1.0f + __expf(-v));
}
__device__ __forceinline__ unsigned short f2bf(float v){
  __hip_bfloat16 b = __float2bfloat16(v);
  return *reinterpret_cast<unsigned short*>(&b);
}
__device__ __forceinline__ float bf2f(unsigned short u){
  unsigned int x = ((unsigned int)u) << 16;
  return __uint_as_float(x);
}
// bijective XCD-chunked swizzle
__device__ __forceinline__ int xcd_swz(int bid, int nwg){
  int q = nwg >> 3, r = nwg & 7;
  int x = bid & 7, w = bid >> 3;
  return (x < r) ? (x*(q+1) + w) : (r*(q+1) + (x-r)*q + w);
}

// ---------------- fused embedding (both graphs) + position copy ----------------
__global__ void k_embed2(const float* __restrict__ lx, const float* __restrict__ px,
                         const float* __restrict__ lpos, const float* __restrict__ ppos,
                         const float* __restrict__ Wl, const float* __restrict__ bl,
                         const float* __restrict__ Wp, const float* __restrict__ bp,
                         float* __restrict__ hl, unsigned short* __restrict__ hbl,
                         float* __restrict__ hp, unsigned short* __restrict__ hbp,
                         float* __restrict__ xl, float* __restrict__ xp){
  int bid = blockIdx.x;
  int g = (bid < NLIG/2) ? 0 : 1;
  int nb = (g ? bid - NLIG/2 : bid) * 2;
  const float* x  = g ? px : lx;
  const float* W  = g ? Wp : Wl;
  const float* b  = g ? bp : bl;
  float* h = g ? hp : hl;
  unsigned short* hb = g ? hbp : hbl;
  int F = g ? FPOC : FLIG;
  int tid = threadIdx.x;
  int n = nb + (tid >> 7);
  int j = tid & 127;
  float acc = b[j];
  for (int k = 0; k < F; k++) acc += x[n*F + k] * W[k*H + j];
  h[(size_t)n*H + j] = acc;
  hb[(size_t)n*H + j] = f2bf(acc);
  if (tid < 6){
    const float* pos = g ? ppos : lpos;
    float* xd = g ? xp : xl;
    xd[(size_t)nb*3 + tid] = pos[(size_t)nb*3 + tid];
  }
}

// ---------------- fused degree histogram ----------------
__global__ void k_hist2(const int* __restrict__ ldst, const int* __restrict__ pdst,
                        int* __restrict__ deg_l, int* __restrict__ deg_p){
  int e = blockIdx.x*256 + threadIdx.x;
  if (e < ELIG) atomicAdd(&deg_l[ldst[e]], 1);
  else if (e < ELIG+EPOC) atomicAdd(&deg_p[pdst[e-ELIG]], 1);
}

// ---------------- both exclusive scans, one dispatch ----------------
__global__ void k_scan2(const int* __restrict__ deg_l, int* __restrict__ offs_l,
                        const int* __restrict__ deg_p, int* __restrict__ offs_p){
  __shared__ int part[1024];
  const int* deg = blockIdx.x ? deg_p : deg_l;
  int* offs = blockIdx.x ? offs_p : offs_l;
  int N = blockIdx.x ? NPOC : NLIG;
  int E = blockIdx.x ? EPOC : ELIG;
  int t = threadIdx.x;
  int chunk = (N + 1023) >> 10;
  int b0 = t*chunk;
  int b1 = b0 + chunk; if (b1 > N) b1 = N;
  int s = 0;
  for (int i = b0; i < b1; i++) s += deg[i];
  part[t] = s;
  __syncthreads();
  for (int off = 1; off < 1024; off <<= 1){
    int v = (t >= off) ? part[t-off] : 0;
    __syncthreads();
    part[t] += v;
    __syncthreads();
  }
  int run = part[t] - s;
  for (int i = b0; i < b1; i++){ offs[i] = run; run += deg[i]; }
  if (t == 1023) offs[N] = E;
}

// ---------------- fused counting-sort scatter ----------------
__global__ void k_sort2(const int* __restrict__ lsrc, const int* __restrict__ ldst,
                        const int* __restrict__ psrc, const int* __restrict__ pdst,
                        const int* __restrict__ offs_l, const int* __restrict__ offs_p,
                        int* __restrict__ cur_l, int* __restrict__ cur_p,
                        int* __restrict__ ssrc_l, int* __restrict__ sdst_l,
                        int* __restrict__ ssrc_p, int* __restrict__ sdst_p){
  int e = blockIdx.x*256 + threadIdx.x;
  if (e < ELIG){
    int d = ldst[e];
    int p = offs_l[d] + atomicAdd(&cur_l[d], 1);
    ssrc_l[p] = lsrc[e]; sdst_l[p] = d;
  } else if (e < ELIG+EPOC){
    int ee = e - ELIG;
    int d = pdst[ee];
    int p = offs_p[d] + atomicAdd(&cur_p[d], 1);
    ssrc_p[p] = psrc[ee]; sdst_p[p] = d;
  }
}

// ---------------- weight packer: MFMA fragment order, fp32 -> bf16 ----------------
__global__ void k_pack(const float* __restrict__ We1, const float* __restrict__ We2,
                       const float* __restrict__ Wh1, const float* __restrict__ Wh2,
                       const float* __restrict__ Wl, const float* __restrict__ bl,
                       const float* __restrict__ Wd1, const float* __restrict__ Wd2,
                       unsigned short* __restrict__ We1p, unsigned short* __restrict__ We2p,
                       unsigned short* __restrict__ Wh1p, unsigned short* __restrict__ Wh2p,
                       unsigned short* __restrict__ W1p, unsigned short* __restrict__ Wd2p)
{
  int idx = blockIdx.x*256 + threadIdx.x;
  const int nWe1 = 6*G1S, nWe2 = 6*G2S, nWh1 = 6*G1S, nWh2 = 6*G2S, nW1 = 16*W1FS, nWd2 = WD2S;
  int i = idx;
  if (i < nWe1){
    int j = i&7, l = (i>>3)&63, t = (i>>9)&7, ks = (i>>12)&7, g = i>>15;
    int k = 32*ks + 8*(l>>4) + j, col = 16*t + (l&15);
    We1p[i] = f2bf(We1[((size_t)g*257 + k)*H + col]);
    return;
  }
  i -= nWe1;
  if (i < nWe2){
    int j = i&7, l = (i>>3)&63, t = (i>>9)&7, ks = (i>>12)&3, g = i>>14;
    int k = 32*ks + 8*(l>>4) + j, col = 16*t + (l&15);
    We2p[i] = f2bf(We2[((size_t)g*H + k)*H + col]);
    return;
  }
  i -= nWe2;
  if (i < nWh1){
    int j = i&7, l = (i>>3)&63, t = (i>>9)&7, ks = (i>>12)&7, g = i>>15;
    int k = 32*ks + 8*(l>>4) + j, col = 16*t + (l&15);
    Wh1p[i] = f2bf(Wh1[((size_t)g*256 + k)*H + col]);
    return;
  }
  i -= nWh1;
  if (i < nWh2){
    int j = i&7, l = (i>>3)&63, t = (i>>9)&7, ks = (i>>12)&3, g = i>>14;
    int k = 32*ks + 8*(l>>4) + j, col = 16*t + (l&15);
    Wh2p[i] = f2bf(Wh2[((size_t)g*H + k)*H + col]);
    return;
  }
  i -= nWh2;
  if (i < nW1){
    int f = i / W1FS, r = i % W1FS;
    int ks = r / (6*512), r2 = r % (6*512);
    int t = r2 / 512, l = (r2 % 512) >> 3, j = r2 & 7;
    int k = 32*ks + 8*(l>>4) + j, col = 16*t + (l&15);
    float v = 0.f;
    if (col < 85) v = (Wl[f*H + k] + bl[k]) * Wd1[k*85 + col];
    W1p[i] = f2bf(v);
    return;
  }
  i -= nW1;
  if (i < nWd2){
    int ks = i / (3*512), r2 = i % (3*512);
    int t = r2 / 512, l = (r2 % 512) >> 3, j = r2 & 7;
    int k = 32*ks + 8*(l>>4) + j, col = 16*t + (l&15);
    float v = 0.f;
    if (k < 85 && col < 43) v = Wd2[k*43 + col];
    Wd2p[i] = f2bf(v);
  }
}

// ---------------- fused edge MLP (bf16 MFMA), 128 edges/block, 2 tiles/wave ----------------
// Wave-private preamble, single barrier; GEMM1 split into two 4-coltile passes
// (#pragma unroll 1) to cap live accumulators at 32 regs during the A-frag-heavy phase.
__global__ __launch_bounds__(256, 3) void k_edge_f(
    const unsigned short* __restrict__ hb_l, const unsigned short* __restrict__ hb_p,
    const float* __restrict__ x_l, const float* __restrict__ x_p,
    const int* __restrict__ ssrc_l, const int* __restrict__ sdst_l,
    const int* __restrict__ ssrc_p, const int* __restrict__ sdst_p,
    const unsigned short* __restrict__ We1pb, const float* __restrict__ We1b,
    const float* __restrict__ be1b,
    const unsigned short* __restrict__ We2pb, const float* __restrict__ be2b,
    const float* __restrict__ Wxb, const float* __restrict__ bxb,
    unsigned short* __restrict__ m2e_l, float* __restrict__ relcf_l,
    unsigned short* __restrict__ m2e_p, float* __restrict__ relcf_p,
    int layer)
{
  __shared__ __align__(16) unsigned short m_lds[128*136]; // col-major [k][edge] s=136; overlay m2t [e][136]
  __shared__ float relS[128][3];
  __shared__ float d2S[128];
  __shared__ int sI[128], dI[128];
  unsigned short* m2t = m_lds;

  int tid = threadIdx.x;
  int bid = xcd_swz(blockIdx.x, NBLK_EL + NBLK_EP);
  int g = (bid < NBLK_EL) ? 0 : 1;
  int e0 = (g ? bid - NBLK_EL : bid) * EPB;
  const unsigned short* hb = g ? hb_p : hb_l;
  const float* x = g ? x_p : x_l;
  const int* ssrc = g ? ssrc_p : ssrc_l;
  const int* sdst = g ? sdst_p : sdst_l;
  unsigned short* m2e = g ? m2e_p : m2e_l;
  float* relcf = g ? relcf_p : relcf_l;
  int gl = g*NLAYERS + layer;
  const unsigned short* We1p = We1pb + (size_t)gl*G1S;
  const unsigned short* We2p = We2pb + (size_t)gl*G2S;
  const float* We1r256 = We1b + ((size_t)gl*257 + 256)*H;
  const float* be1 = be1b + (size_t)gl*H;
  const float* be2 = be2b + (size_t)gl*H;
  const float* Wx = Wxb + (size_t)gl*H;

  int lane = tid & 63, wave = tid >> 6;
  int c = lane & 15, q = lane >> 4;

  // wave-private preamble: indices + rel/d2 for this wave's 32 edges (no barrier)
  if (lane < 32){
    int e = wave*32 + lane;
    int s = ssrc[e0+e], d = sdst[e0+e];
    sI[e] = s; dI[e] = d;
    float rx = x[d*3+0]-x[s*3+0];
    float ry = x[d*3+1]-x[s*3+1];
    float rz = x[d*3+2]-x[s*3+2];
    relS[e][0]=rx; relS[e][1]=ry; relS[e][2]=rz;
    d2S[e] = rx*rx+ry*ry+rz*rz;
  }

  int eA = wave*32 + c;          // tile0 A-row
  int eB = eA + 16;              // tile1 A-row
  const unsigned short* pD0 = hb + (size_t)dI[eA]*H + q*8;
  const unsigned short* pS0 = hb + (size_t)sI[eA]*H + q*8;
  const unsigned short* pD1 = hb + (size_t)dI[eB]*H + q*8;
  const unsigned short* pS1 = hb + (size_t)sI[eB]*H + q*8;

  // full A-frag prefetch, both tiles (16 x s8)
  s8 af0[8], af1[8];
  #pragma unroll
  for (int ks=0; ks<4; ks++){
    af0[ks]   = *(const s8*)(pD0 + ks*32);
    af0[4+ks] = *(const s8*)(pS0 + ks*32);
    af1[ks]   = *(const s8*)(pD1 + ks*32);
    af1[4+ks] = *(const s8*)(pS1 + ks*32);
  }

  int er0 = wave*32 + 4*q;
  int er1 = er0 + 16;
  float d20[4], d21[4];
  #pragma unroll
  for (int i=0;i<4;i++){ d20[i] = d2S[er0+i]; d21[i] = d2S[er1+i]; }

  // ---- GEMM1 (K=256), two sequential 4-coltile passes (acc capped at 32 regs) ----
  const s8* B1 = (const s8*)We1p;
  #pragma unroll 1
  for (int hh=0; hh<2; hh++){
    f32x4 acc0[4], acc1[4];
    #pragma unroll
    for (int t=0;t<4;t++){ acc0[t] = (f32x4){0.f,0.f,0.f,0.f}; acc1[t] = (f32x4){0.f,0.f,0.f,0.f}; }
    #pragma unroll
    for (int ks=0; ks<8; ks++){
      const s8* bp = B1 + (ks*8 + hh*4)*64 + lane;
      #pragma unroll
      for (int t=0;t<4;t++){
        s8 B = bp[t*64];
        acc0[t] = __builtin_amdgcn_mfma_f32_16x16x32_bf16(af0[ks], B, acc0[t], 0,0,0);
        acc1[t] = __builtin_amdgcn_mfma_f32_16x16x32_bf16(af1[ks], B, acc1[t], 0,0,0);
      }
    }
    #pragma unroll
    for (int t=0;t<4;t++){
      int j2 = 16*(hh*4+t) + c;
      float w256 = We1r256[j2], bias = be1[j2];
      s4 mv0, mv1;
      #pragma unroll
      for (int i=0;i<4;i++){
        mv0[i] = (short)f2bf(silu_f(acc0[t][i] + d20[i]*w256 + bias));
        mv1[i] = (short)f2bf(silu_f(acc1[t][i] + d21[i]*w256 + bias));
      }
      *(s4*)&m_lds[136*j2 + er0] = mv0;   // wave-private edge columns
      *(s4*)&m_lds[136*j2 + er1] = mv1;
    }
  }

  // ---- GEMM2 (K=128), wave-private m_lds reads, B shared across tiles ----
  f32x4 acc0[8], acc1[8];
  #pragma unroll
  for (int t=0;t<8;t++){ acc0[t] = (f32x4){0.f,0.f,0.f,0.f}; acc1[t] = (f32x4){0.f,0.f,0.f,0.f}; }
  const s8* B2 = (const s8*)We2p;
  #pragma unroll
  for (int ks=0; ks<4; ks++){
    s8 a20, a21;
    int base = 136*(32*ks + 8*q) + wave*32 + c;
    #pragma unroll
    for (int j=0;j<8;j++){
      a20[j] = (short)m_lds[base + 136*j];
      a21[j] = (short)m_lds[base + 16 + 136*j];
    }
    const s8* bp = B2 + (ks*8)*64 + lane;
    #pragma unroll
    for (int t=0;t<8;t++){
      s8 B = bp[t*64];
      acc0[t] = __builtin_amdgcn_mfma_f32_16x16x32_bf16(a20, B, acc0[t], 0,0,0);
      acc1[t] = __builtin_amdgcn_mfma_f32_16x16x32_bf16(a21, B, acc1[t], 0,0,0);
    }
  }
  __syncthreads();   // ONLY barrier: m_lds (all waves' reads) -> m2t overlay (cross-wave clobber)

  // epilogue: silu + coef partials; m2 bf16 into transpose LDS (row-major [e][136])
  float pp0[4] = {0.f,0.f,0.f,0.f};
  float pp1[4] = {0.f,0.f,0.f,0.f};
  #pragma unroll
  for (int t=0;t<8;t++){
    int j2 = 16*t + c;
    float b2v = be2[j2], wxv = Wx[j2];
    #pragma unroll
    for (int i=0;i<4;i++){
      float v0 = silu_f(acc0[t][i] + b2v);
      float v1 = silu_f(acc1[t][i] + b2v);
      pp0[i] += v0*wxv;
      pp1[i] += v1*wxv;
      m2t[(er0+i)*136 + j2] = f2bf(v0);
      m2t[(er1+i)*136 + j2] = f2bf(v1);
    }
  }
  #pragma unroll
  for (int off=1; off<16; off<<=1){
    #pragma unroll
    for (int i=0;i<4;i++){
      pp0[i] += __shfl_xor(pp0[i], off, 64);
      pp1[i] += __shfl_xor(pp1[i], off, 64);
    }
  }
  if (c == 0){
    float bxv = bxb[gl];
    #pragma unroll
    for (int i=0;i<4;i++){
      int e = er0 + i;
      float cf = pp0[i] + bxv;
      float* rp = relcf + (size_t)(e0+e)*3;
      rp[0] = relS[e][0]*cf; rp[1] = relS[e][1]*cf; rp[2] = relS[e][2]*cf;
      e = er1 + i;
      cf = pp1[i] + bxv;
      rp = relcf + (size_t)(e0+e)*3;
      rp[0] = relS[e][0]*cf; rp[1] = relS[e][1]*cf; rp[2] = relS[e][2]*cf;
    }
  }

  // coalesced m2 store: lane -> (own wave's edge, 64-col half); wave-private m2t rows
  {
    int e = wave*32 + (lane >> 1), cb = (lane & 1) * 64;
    const s8* sp = (const s8*)&m2t[e*136 + cb];
    s8* dp = (s8*)(m2e + (size_t)(e0+e)*H + cb);
    #pragma unroll
    for (int s2=0; s2<8; s2++) dp[s2] = sp[s2];
  }
}

// ---------------- fused node update: CSR reduce + bf16 MFMA, barrier-free ----------------
__global__ __launch_bounds__(128, 4) void k_node_f(
    float* __restrict__ h_l, unsigned short* __restrict__ hb_l, float* __restrict__ x_l,
    float* __restrict__ h_p, unsigned short* __restrict__ hb_p, float* __restrict__ x_p,
    const unsigned short* __restrict__ m2e_l, const float* __restrict__ relcf_l,
    const unsigned short* __restrict__ m2e_p, const float* __restrict__ relcf_p,
    const int* __restrict__ offs_l, const int* __restrict__ offs_p,
    const unsigned short* __restrict__ Wh1pb, const float* __restrict__ bh1b,
    const unsigned short* __restrict__ Wh2pb, const float* __restrict__ bh2b,
    int layer)
{
  __shared__ __align__(16) unsigned short aggS[32*136];   // agg_m bf16, [node][col] stride 136
  __shared__ __align__(16) unsigned short u_lds[128*36];
  __shared__ float rcS[32][3];
  __shared__ int degS[32];

  int tid = threadIdx.x;
  int bid = xcd_swz(blockIdx.x, NBLK_NL + NBLK_NP);
  int g = (bid < NBLK_NL) ? 0 : 1;
  int nb0 = (g ? bid - NBLK_NL : bid) * 32;
  int N = g ? NPOC : NLIG;
  float* h = g ? h_p : h_l;
  unsigned short* hbm = g ? hb_p : hb_l;
  float* x = g ? x_p : x_l;
  const unsigned short* m2e = g ? m2e_p : m2e_l;
  const float* relcf = g ? relcf_p : relcf_l;
  const int* offs = g ? offs_p : offs_l;
  int gl = g*NLAYERS + layer;
  const unsigned short* Wh1p = Wh1pb + (size_t)gl*G1S;
  const unsigned short* Wh2p = Wh2pb + (size_t)gl*G2S;
  const float* bh1 = bh1b + (size_t)gl*H;
  const float* bh2 = bh2b + (size_t)gl*H;

  int lane = tid & 63, wave = tid >> 6;

  // ---- phase A: CSR reduce; wave w owns nodes [w*16, w*16+16) (wave-private) ----
  {
    int nloc = tid >> 2, cb = (tid & 3) * 32;
    int gn = nb0 + nloc;
    int gna = (gn < N) ? gn : (N-1);
    int o0 = offs[gna], o1 = offs[gna+1];
    float sums[32];
    #pragma unroll
    for (int k=0;k<32;k++) sums[k] = 0.f;
    float rc0=0.f, rc1=0.f, rc2=0.f;
    bool rc_owner = (tid & 3) == 0;
    for (int e = o0; e < o1; e++){
      const unsigned short* mp = m2e + (size_t)e*H + cb;
      #pragma unroll
      for (int s2=0; s2<4; s2++){
        s8 v = *(const s8*)(mp + s2*8);
        #pragma unroll
        for (int j=0;j<8;j++)
          sums[s2*8+j] += bf2f((unsigned short)v[j]);
      }
      if (rc_owner){
        const float* rp = relcf + (size_t)e*3;
        rc0 += rp[0]; rc1 += rp[1]; rc2 += rp[2];
      }
    }
    unsigned short* ap = &aggS[nloc*136 + cb];
    #pragma unroll
    for (int s2=0; s2<4; s2++){
      s8 vv;
      #pragma unroll
      for (int j=0;j<8;j++) vv[j] = (short)f2bf(sums[s2*8+j]);
      *(s8*)(ap + s2*8) = vv;
    }
    if (rc_owner){
      rcS[nloc][0] = rc0; rcS[nloc][1] = rc1; rcS[nloc][2] = rc2;
      degS[nloc] = o1 - o0;
    }
  }

  // x update: wave-aligned (wave w -> its own nodes), no barrier needed
  if (lane < 48){
    int nn = wave*16 + lane/3, cc = lane - (lane/3)*3;
    int gn = nb0 + nn;
    if (gn < N){
      float dv = (float)degS[nn]; if (dv < 1.f) dv = 1.f;
      x[(size_t)gn*3 + cc] += rcS[nn][cc] / dv;
    }
  }

  int c = lane & 15, q = lane >> 4;
  int node = nb0 + wave*16 + c;
  int na = node < N ? node : N-1;
  int nloc2 = wave*16 + c;

  // A frags: ks 0..3 = h (bf16 mirror), ks 4..7 = aggS (bf16, wave-private rows)
  s8 af[8];
  #pragma unroll
  for (int ks=0; ks<4; ks++)
    af[ks] = *(const s8*)(hbm + (size_t)na*H + ks*32 + q*8);
  #pragma unroll
  for (int ks=4; ks<8; ks++)
    af[ks] = *(const s8*)&aggS[nloc2*136 + (ks-4)*32 + q*8];

  f32x4 acc[8];
  #pragma unroll
  for (int t=0;t<8;t++) acc[t] = (f32x4){0.f,0.f,0.f,0.f};
  const s8* B1 = (const s8*)Wh1p;
  #pragma unroll
  for (int ks=0; ks<8; ks++){
    const s8* bp = B1 + (ks*8)*64 + lane;
    #pragma unroll
    for (int t=0;t<8;t++)
      acc[t] = __builtin_amdgcn_mfma_f32_16x16x32_bf16(af[ks], bp[t*64], acc[t], 0,0,0);
  }

  int er0 = wave*16 + 4*q;
  #pragma unroll
  for (int t=0;t<8;t++){
    int j2 = 16*t + c;
    float b1 = bh1[j2];
    s4 mv;
    #pragma unroll
    for (int i=0;i<4;i++) mv[i] = (short)f2bf(silu_f(acc[t][i] + b1));
    *(s4*)&u_lds[36*j2 + er0] = mv;   // wave-private rows
  }

  f32x4 acc2[8];
  #pragma unroll
  for (int t=0;t<8;t++) acc2[t] = (f32x4){0.f,0.f,0.f,0.f};
  const s8* B2 = (const s8*)Wh2p;
  #pragma unroll
  for (int ks=0; ks<4; ks++){
    s8 a2;
    int base = 36*(32*ks + 8*q) + wave*16 + c;
    #pragma unroll
    for (int j=0;j<8;j++) a2[j] = (short)u_lds[base + 36*j];
    const s8* bp = B2 + (ks*8)*64 + lane;
    #pragma unroll
    for (int t=0;t<8;t++)
      acc2[t] = __builtin_amdgcn_mfma_f32_16x16x32_bf16(a2, bp[t*64], acc2[t], 0,0,0);
  }

  #pragma unroll
  for (int t=0;t<8;t++){
    int j2 = 16*t + c;
    float b2 = bh2[j2];
    #pragma unroll
    for (int i=0;i<4;i++){
      int gr = nb0 + wave*16 + 4*q + i;
      if (gr < N){
        size_t off = (size_t)gr*H + j2;
        float hv = h[off] + acc2[t][i] + b2;
        h[off] = hv;
        hbm[off] = f2bf(hv);
      }
    }
  }
}

// ---------------- NextType head via bf16 MFMA, 8 waves, f-parallel ----------------
__global__ __launch_bounds__(512, 2) void k_head3(
    const unsigned short* __restrict__ hb, const int* __restrict__ batch,
    const unsigned short* __restrict__ W1p, const float* __restrict__ bd1,
    const unsigned short* __restrict__ Wd2p, const float* __restrict__ bd2,
    const float* __restrict__ Wd3, const float* __restrict__ bd3,
    float* __restrict__ agg, int N)
{
  __shared__ __align__(16) unsigned short t1tr[96*132];
  __shared__ float t3s[32][18];
  __shared__ float lgs[32][18];
  __shared__ int bI[32];

  int tid = threadIdx.x;
  int nb0 = blockIdx.x * 32;
  int lane = tid & 63, wave = tid >> 6;
  int pair = wave >> 1, sub = wave & 1;
  int c = lane & 15, q = lane >> 4;

  int node = nb0 + sub*16 + c;
  int na = node < N ? node : N-1;

  s8 ah[4];
  #pragma unroll
  for (int ks=0; ks<4; ks++)
    ah[ks] = *(const s8*)(hb + (size_t)na*H + ks*32 + q*8);

  float b1c[6];
  #pragma unroll
  for (int t=0;t<6;t++){ int col=16*t+c; b1c[t] = (col<85) ? bd1[col] : 0.f; }
  float b2c[3], w3c[3];
  #pragma unroll
  for (int t=0;t<3;t++){
    int col=16*t+c;
    b2c[t] = (col<43) ? bd2[col] : 0.f;
    w3c[t] = (col<43) ? Wd3[col] : 0.f;
  }
  float bd3v = bd3[0];
  int rbase = wave*16;
  int er0 = rbase + 4*q;

  for (int fi=0; fi<4; fi++){
    int f = pair + 4*fi;
    const s8* B1 = (const s8*)W1p + f*(W1FS/8);
    f32x4 acc[6];
    #pragma unroll
    for (int t=0;t<6;t++) acc[t] = (f32x4){0.f,0.f,0.f,0.f};
    #pragma unroll
    for (int ks=0; ks<4; ks++){
      #pragma unroll
      for (int t=0;t<6;t++)
        acc[t] = __builtin_amdgcn_mfma_f32_16x16x32_bf16(ah[ks], B1[(ks*6+t)*64+lane], acc[t], 0,0,0);
    }
    #pragma unroll
    for (int t=0;t<6;t++){
      int j2 = 16*t + c;
      s4 mv;
      #pragma unroll
      for (int i=0;i<4;i++) mv[i] = (short)f2bf(silu_f(acc[t][i] + b1c[t]));
      *(s4*)&t1tr[132*j2 + er0] = mv;
    }
    f32x4 acc2[3];
    #pragma unroll
    for (int t=0;t<3;t++) acc2[t] = (f32x4){0.f,0.f,0.f,0.f};
    const s8* B2 = (const s8*)Wd2p;
    #pragma unroll
    for (int ks=0; ks<3; ks++){
      s8 a2;
      int base = 132*(32*ks + 8*q) + rbase + c;
      #pragma unroll
      for (int j=0;j<8;j++) a2[j] = (short)t1tr[base + 132*j];
      #pragma unroll
      for (int t=0;t<3;t++)
        acc2[t] = __builtin_amdgcn_mfma_f32_16x16x32_bf16(a2, B2[(ks*3+t)*64+lane], acc2[t], 0,0,0);
    }
    float pp[4] = {0.f,0.f,0.f,0.f};
    #pragma unroll
    for (int t=0;t<3;t++){
      #pragma unroll
      for (int i=0;i<4;i++) pp[i] += silu_f(acc2[t][i] + b2c[t]) * w3c[t];
    }
    #pragma unroll
    for (int off=1; off<16; off<<=1){
      #pragma unroll
      for (int i=0;i<4;i++) pp[i] += __shfl_xor(pp[i], off, 64);
    }
    if (c == 0){
      #pragma unroll
      for (int i=0;i<4;i++) t3s[sub*16 + 4*q + i][f] = pp[i] + bd3v;
    }
  }
  __syncthreads();

  if (tid < 32){
    int n = nb0 + tid;
    bool valid = n < N;
    bI[tid] = batch[valid ? n : (N-1)];
    if (valid){
      float m = t3s[tid][0];
      #pragma unroll
      for (int i=1;i<16;i++) m = fmaxf(m, t3s[tid][i]);
      float s = 0.f;
      #pragma unroll
      for (int i=0;i<16;i++) s += __expf(t3s[tid][i] - m);
      float ls = __logf(s);
      #pragma unroll
      for (int i=0;i<16;i++) lgs[tid][i] = t3s[tid][i] - m - ls;
    } else {
      #pragma unroll
      for (int i=0;i<16;i++) lgs[tid][i] = 0.f;
    }
  }
  __syncthreads();

  if (tid < 16){
    int f = tid;
    float acc = 0.f; int run = bI[0];
    for (int n = 0; n < 32; n++){
      int b = bI[n];
      if (b != run){ atomicAdd(&agg[run*16 + f], acc); acc = 0.f; run = b; }
      acc += lgs[n][f];
    }
    atomicAdd(&agg[run*16 + f], acc);
  }
}

// ---------------- final: out = agg - logsumexp(agg) ----------------
__global__ void k_final(const float* __restrict__ agg, float* __restrict__ out){
  int tid = threadIdx.x;
  float vv = agg[tid];
  float m = vv;
  #pragma unroll
  for (int off = 1; off < 16; off <<= 1) m = fmaxf(m, __shfl_xor(m, off, 64));
  float s = __expf(vv - m);
  #pragma unroll
  for (int off = 1; off < 16; off <<= 1) s += __shfl_xor(s, off, 64);
  out[tid] = vv - m - __logf(s);
}

extern "C" void kernel_launch(void* const* d_in, const int* in_sizes, int n_in,
                              void* d_out, int out_size, void* d_ws, size_t ws_size,
                              hipStream_t stream)
{
  const float* ligand_x   = (const float*)d_in[0];
  const float* pocket_x   = (const float*)d_in[1];
  const float* ligand_pos = (const float*)d_in[2];
  const float* pocket_pos = (const float*)d_in[3];
  const float* Wl_emb = (const float*)d_in[4];
  const float* bl_emb = (const float*)d_in[5];
  const float* Wp_emb = (const float*)d_in[6];
  const float* bp_emb = (const float*)d_in[7];
  const float* We1 = (const float*)d_in[8];
  const float* be1 = (const float*)d_in[9];
  const float* We2 = (const float*)d_in[10];
  const float* be2 = (const float*)d_in[11];
  const float* Wx  = (const float*)d_in[12];
  const float* bx  = (const float*)d_in[13];
  const float* Wh1 = (const float*)d_in[14];
  const float* bh1 = (const float*)d_in[15];
  const float* Wh2 = (const float*)d_in[16];
  const float* bh2 = (const float*)d_in[17];
  const float* Wd1 = (const float*)d_in[18];
  const float* bd1 = (const float*)d_in[19];
  const float* Wd2 = (const float*)d_in[20];
  const float* bd2 = (const float*)d_in[21];
  const float* Wd3 = (const float*)d_in[22];
  const float* bd3 = (const float*)d_in[23];
  const int* l2l    = (const int*)d_in[24];
  const int* p2p    = (const int*)d_in[25];
  const int* lbatch = (const int*)d_in[26];

  char* w = (char*)d_ws;
  auto alloc = [&](size_t bytes)->char*{
    char* p = w; w += (bytes + 255) & ~(size_t)255; return p;
  };
  float* hl    = (float*)alloc((size_t)NLIG*H*4);
  float* hp    = (float*)alloc((size_t)NPOC*H*4);
  unsigned short* hbl = (unsigned short*)alloc((size_t)NLIG*H*2);
  unsigned short* hbp = (unsigned short*)alloc((size_t)NPOC*H*2);
  float* xl    = (float*)alloc((size_t)NLIG*3*4);
  float* xp    = (float*)alloc((size_t)NPOC*3*4);
  int* offs_l = (int*)alloc((size_t)(NLIG+1)*4);
  int* offs_p = (int*)alloc((size_t)(NPOC+1)*4);
  int* ssrc_l = (int*)alloc((size_t)ELIG*4);
  int* sdst_l = (int*)alloc((size_t)ELIG*4);
  int* ssrc_p = (int*)alloc((size_t)EPOC*4);
  int* sdst_p = (int*)alloc((size_t)EPOC*4);
  unsigned short* We1p = (unsigned short*)alloc((size_t)6*G1S*2);
  unsigned short* We2p = (unsigned short*)alloc((size_t)6*G2S*2);
  unsigned short* Wh1p = (unsigned short*)alloc((size_t)6*G1S*2);
  unsigned short* Wh2p = (unsigned short*)alloc((size_t)6*G2S*2);
  unsigned short* W1p  = (unsigned short*)alloc((size_t)16*W1FS*2);
  unsigned short* Wd2p = (unsigned short*)alloc((size_t)WD2S*2);
  unsigned short* m2e_l = (unsigned short*)alloc((size_t)ELIG*H*2);
  unsigned short* m2e_p = (unsigned short*)alloc((size_t)EPOC*H*2);
  float* relcf_l = (float*)alloc((size_t)ELIG*3*4);
  float* relcf_p = (float*)alloc((size_t)EPOC*3*4);
  // ---- contiguous zero-init region ----
  char* zbase = w;
  int* deg_l = (int*)alloc((size_t)NLIG*4);
  int* deg_p = (int*)alloc((size_t)NPOC*4);
  int* cur_l = (int*)alloc((size_t)NLIG*4);
  int* cur_p = (int*)alloc((size_t)NPOC*4);
  float* aggB = (float*)alloc((size_t)NB*16*4);
  size_t zsize = (size_t)(w - zbase);

  hipMemsetAsync(zbase, 0, zsize, stream);

  const int* lsrc = l2l;          const int* ldst = l2l + ELIG;
  const int* psrc = p2p;          const int* pdst = p2p + EPOC;

  k_embed2<<<NLIG/2 + NPOC/2, 256, 0, stream>>>(ligand_x, pocket_x, ligand_pos, pocket_pos,
      Wl_emb, bl_emb, Wp_emb, bp_emb, hl, hbl, hp, hbp, xl, xp);
  k_hist2<<<(ELIG+EPOC+255)/256, 256, 0, stream>>>(ldst, pdst, deg_l, deg_p);
  k_scan2<<<2, 1024, 0, stream>>>(deg_l, offs_l, deg_p, offs_p);
  k_sort2<<<(ELIG+EPOC+255)/256, 256, 0, stream>>>(lsrc, ldst, psrc, pdst,
      offs_l, offs_p, cur_l, cur_p, ssrc_l, sdst_l, ssrc_p, sdst_p);
  {
    int npack = 6*G1S + 6*G2S + 6*G1S + 6*G2S + 16*W1FS + WD2S;
    k_pack<<<(npack+255)/256, 256, 0, stream>>>(We1, We2, Wh1, Wh2,
        Wl_emb, bl_emb, Wd1, Wd2, We1p, We2p, Wh1p, Wh2p, W1p, Wd2p);
  }

  for (int l = 0; l < NLAYERS; l++){
    k_edge_f<<<NBLK_EL + NBLK_EP, 256, 0, stream>>>(hbl, hbp, xl, xp,
        ssrc_l, sdst_l, ssrc_p, sdst_p,
        We1p, We1, be1, We2p, be2, Wx, bx,
        m2e_l, relcf_l, m2e_p, relcf_p, l);
    k_node_f<<<NBLK_NL + NBLK_NP, 128, 0, stream>>>(hl, hbl, xl, hp, hbp, xp,
        m2e_l, relcf_l, m2e_p, relcf_p, offs_l, offs_p,
        Wh1p, bh1, Wh2p, bh2, l);
  }

  k_head3<<<(NLIG+31)/32, 512, 0, stream>>>(hbl, lbatch, W1p, bd1, Wd2p, bd2,
                                            Wd3, bd3, aggB, NLIG);
  k_final<<<1, 128, 0, stream>>>(aggB, (float*)d_out);
}

// Round 14
// 656.099 us; speedup vs baseline: 2.2583x; 1.2142x over previous
//
#include <hip/hip_runtime.h>
#include <hip/hip_bf16.h>
#include <math.h>

typedef __attribute__((ext_vector_type(4))) float f4;
typedef __attribute__((ext_vector_type(4))) float f32x4;
typedef __attribute__((ext_vector_type(8))) short s8;
typedef __attribute__((ext_vector_type(4))) short s4;

#define H 128
#define NLAYERS 3
#define FLIG 16
#define FPOC 27
#define NLIG 20000
#define NPOC 30000
#define ELIG 160000
#define EPOC 240000
#define NB 8

#define EPB 128                  // edges per block
#define NBLK_EL (ELIG/EPB)       // 1250
#define NBLK_EP (EPOC/EPB)       // 1875
#define NBLK_NL ((NLIG+31)/32)   // 625
#define NBLK_NP ((NPOC+31)/32)   // 938

// packed-weight strides (elements)
#define G1S (8*8*64*8)   // K=256 GEMM1 weights per group (8 ksteps x 8 coltiles)
#define G2S (4*8*64*8)   // K=128 GEMM2 weights per group
#define W1FS (4*6*64*8)  // head W1f per f: 4 ksteps x 6 coltiles
#define WD2S (3*3*64*8)  // head Wd2: 3 ksteps x 3 coltiles

// silu with hw rcp (rel err ~1e-5, far below bf16 eps)
__device__ __forceinline__ float silu_f(float v){
  return v * __builtin_amdgcn_rcpf(1.0f + __expf(-v));
}
__device__ __forceinline__ unsigned short f2bf(float v){
  __hip_bfloat16 b = __float2bfloat16(v);
  return *reinterpret_cast<unsigned short*>(&b);
}
__device__ __forceinline__ float bf2f(unsigned short u){
  unsigned int x = ((unsigned int)u) << 16;
  return __uint_as_float(x);
}
// bijective XCD-chunked swizzle
__device__ __forceinline__ int xcd_swz(int bid, int nwg){
  int q = nwg >> 3, r = nwg & 7;
  int x = bid & 7, w = bid >> 3;
  return (x < r) ? (x*(q+1) + w) : (r*(q+1) + (x-r)*q + w);
}

// ---------------- fused embedding (both graphs) + position copy ----------------
__global__ void k_embed2(const float* __restrict__ lx, const float* __restrict__ px,
                         const float* __restrict__ lpos, const float* __restrict__ ppos,
                         const float* __restrict__ Wl, const float* __restrict__ bl,
                         const float* __restrict__ Wp, const float* __restrict__ bp,
                         float* __restrict__ hl, unsigned short* __restrict__ hbl,
                         float* __restrict__ hp, unsigned short* __restrict__ hbp,
                         float* __restrict__ xl, float* __restrict__ xp){
  int bid = blockIdx.x;
  int g = (bid < NLIG/2) ? 0 : 1;
  int nb = (g ? bid - NLIG/2 : bid) * 2;
  const float* x  = g ? px : lx;
  const float* W  = g ? Wp : Wl;
  const float* b  = g ? bp : bl;
  float* h = g ? hp : hl;
  unsigned short* hb = g ? hbp : hbl;
  int F = g ? FPOC : FLIG;
  int tid = threadIdx.x;
  int n = nb + (tid >> 7);
  int j = tid & 127;
  float acc = b[j];
  for (int k = 0; k < F; k++) acc += x[n*F + k] * W[k*H + j];
  h[(size_t)n*H + j] = acc;
  hb[(size_t)n*H + j] = f2bf(acc);
  if (tid < 6){
    const float* pos = g ? ppos : lpos;
    float* xd = g ? xp : xl;
    xd[(size_t)nb*3 + tid] = pos[(size_t)nb*3 + tid];
  }
}

// ---------------- fused degree histogram ----------------
__global__ void k_hist2(const int* __restrict__ ldst, const int* __restrict__ pdst,
                        int* __restrict__ deg_l, int* __restrict__ deg_p){
  int e = blockIdx.x*256 + threadIdx.x;
  if (e < ELIG) atomicAdd(&deg_l[ldst[e]], 1);
  else if (e < ELIG+EPOC) atomicAdd(&deg_p[pdst[e-ELIG]], 1);
}

// ---------------- both exclusive scans, one dispatch ----------------
__global__ void k_scan2(const int* __restrict__ deg_l, int* __restrict__ offs_l,
                        const int* __restrict__ deg_p, int* __restrict__ offs_p){
  __shared__ int part[1024];
  const int* deg = blockIdx.x ? deg_p : deg_l;
  int* offs = blockIdx.x ? offs_p : offs_l;
  int N = blockIdx.x ? NPOC : NLIG;
  int E = blockIdx.x ? EPOC : ELIG;
  int t = threadIdx.x;
  int chunk = (N + 1023) >> 10;
  int b0 = t*chunk;
  int b1 = b0 + chunk; if (b1 > N) b1 = N;
  int s = 0;
  for (int i = b0; i < b1; i++) s += deg[i];
  part[t] = s;
  __syncthreads();
  for (int off = 1; off < 1024; off <<= 1){
    int v = (t >= off) ? part[t-off] : 0;
    __syncthreads();
    part[t] += v;
    __syncthreads();
  }
  int run = part[t] - s;
  for (int i = b0; i < b1; i++){ offs[i] = run; run += deg[i]; }
  if (t == 1023) offs[N] = E;
}

// ---------------- fused counting-sort scatter ----------------
__global__ void k_sort2(const int* __restrict__ lsrc, const int* __restrict__ ldst,
                        const int* __restrict__ psrc, const int* __restrict__ pdst,
                        const int* __restrict__ offs_l, const int* __restrict__ offs_p,
                        int* __restrict__ cur_l, int* __restrict__ cur_p,
                        int* __restrict__ ssrc_l, int* __restrict__ sdst_l,
                        int* __restrict__ ssrc_p, int* __restrict__ sdst_p){
  int e = blockIdx.x*256 + threadIdx.x;
  if (e < ELIG){
    int d = ldst[e];
    int p = offs_l[d] + atomicAdd(&cur_l[d], 1);
    ssrc_l[p] = lsrc[e]; sdst_l[p] = d;
  } else if (e < ELIG+EPOC){
    int ee = e - ELIG;
    int d = pdst[ee];
    int p = offs_p[d] + atomicAdd(&cur_p[d], 1);
    ssrc_p[p] = psrc[ee]; sdst_p[p] = d;
  }
}

// ---------------- weight packer: MFMA fragment order, fp32 -> bf16 ----------------
__global__ void k_pack(const float* __restrict__ We1, const float* __restrict__ We2,
                       const float* __restrict__ Wh1, const float* __restrict__ Wh2,
                       const float* __restrict__ Wl, const float* __restrict__ bl,
                       const float* __restrict__ Wd1, const float* __restrict__ Wd2,
                       unsigned short* __restrict__ We1p, unsigned short* __restrict__ We2p,
                       unsigned short* __restrict__ Wh1p, unsigned short* __restrict__ Wh2p,
                       unsigned short* __restrict__ W1p, unsigned short* __restrict__ Wd2p)
{
  int idx = blockIdx.x*256 + threadIdx.x;
  const int nWe1 = 6*G1S, nWe2 = 6*G2S, nWh1 = 6*G1S, nWh2 = 6*G2S, nW1 = 16*W1FS, nWd2 = WD2S;
  int i = idx;
  if (i < nWe1){
    int j = i&7, l = (i>>3)&63, t = (i>>9)&7, ks = (i>>12)&7, g = i>>15;
    int k = 32*ks + 8*(l>>4) + j, col = 16*t + (l&15);
    We1p[i] = f2bf(We1[((size_t)g*257 + k)*H + col]);
    return;
  }
  i -= nWe1;
  if (i < nWe2){
    int j = i&7, l = (i>>3)&63, t = (i>>9)&7, ks = (i>>12)&3, g = i>>14;
    int k = 32*ks + 8*(l>>4) + j, col = 16*t + (l&15);
    We2p[i] = f2bf(We2[((size_t)g*H + k)*H + col]);
    return;
  }
  i -= nWe2;
  if (i < nWh1){
    int j = i&7, l = (i>>3)&63, t = (i>>9)&7, ks = (i>>12)&7, g = i>>15;
    int k = 32*ks + 8*(l>>4) + j, col = 16*t + (l&15);
    Wh1p[i] = f2bf(Wh1[((size_t)g*256 + k)*H + col]);
    return;
  }
  i -= nWh1;
  if (i < nWh2){
    int j = i&7, l = (i>>3)&63, t = (i>>9)&7, ks = (i>>12)&3, g = i>>14;
    int k = 32*ks + 8*(l>>4) + j, col = 16*t + (l&15);
    Wh2p[i] = f2bf(Wh2[((size_t)g*H + k)*H + col]);
    return;
  }
  i -= nWh2;
  if (i < nW1){
    int f = i / W1FS, r = i % W1FS;
    int ks = r / (6*512), r2 = r % (6*512);
    int t = r2 / 512, l = (r2 % 512) >> 3, j = r2 & 7;
    int k = 32*ks + 8*(l>>4) + j, col = 16*t + (l&15);
    float v = 0.f;
    if (col < 85) v = (Wl[f*H + k] + bl[k]) * Wd1[k*85 + col];
    W1p[i] = f2bf(v);
    return;
  }
  i -= nW1;
  if (i < nWd2){
    int ks = i / (3*512), r2 = i % (3*512);
    int t = r2 / 512, l = (r2 % 512) >> 3, j = r2 & 7;
    int k = 32*ks + 8*(l>>4) + j, col = 16*t + (l&15);
    float v = 0.f;
    if (k < 85 && col < 43) v = Wd2[k*43 + col];
    Wd2p[i] = f2bf(v);
  }
}

// ---------------- fused edge MLP (bf16 MFMA), 128 edges/block, 2 tiles/wave ----------------
// Wave-private preamble + single barrier (only the m_lds->m2t overlay is cross-wave).
__global__ __launch_bounds__(256, 3) void k_edge_f(
    const unsigned short* __restrict__ hb_l, const unsigned short* __restrict__ hb_p,
    const float* __restrict__ x_l, const float* __restrict__ x_p,
    const int* __restrict__ ssrc_l, const int* __restrict__ sdst_l,
    const int* __restrict__ ssrc_p, const int* __restrict__ sdst_p,
    const unsigned short* __restrict__ We1pb, const float* __restrict__ We1b,
    const float* __restrict__ be1b,
    const unsigned short* __restrict__ We2pb, const float* __restrict__ be2b,
    const float* __restrict__ Wxb, const float* __restrict__ bxb,
    unsigned short* __restrict__ m2e_l, float* __restrict__ relcf_l,
    unsigned short* __restrict__ m2e_p, float* __restrict__ relcf_p,
    int layer)
{
  __shared__ __align__(16) unsigned short m_lds[128*136]; // col-major [k][edge] s=136; overlay m2t [e][136]
  __shared__ float relS[128][3];
  __shared__ float d2S[128];
  __shared__ int sI[128], dI[128];
  unsigned short* m2t = m_lds;

  int tid = threadIdx.x;
  int bid = xcd_swz(blockIdx.x, NBLK_EL + NBLK_EP);
  int g = (bid < NBLK_EL) ? 0 : 1;
  int e0 = (g ? bid - NBLK_EL : bid) * EPB;
  const unsigned short* hb = g ? hb_p : hb_l;
  const float* x = g ? x_p : x_l;
  const int* ssrc = g ? ssrc_p : ssrc_l;
  const int* sdst = g ? sdst_p : sdst_l;
  unsigned short* m2e = g ? m2e_p : m2e_l;
  float* relcf = g ? relcf_p : relcf_l;
  int gl = g*NLAYERS + layer;
  const unsigned short* We1p = We1pb + (size_t)gl*G1S;
  const unsigned short* We2p = We2pb + (size_t)gl*G2S;
  const float* We1r256 = We1b + ((size_t)gl*257 + 256)*H;
  const float* be1 = be1b + (size_t)gl*H;
  const float* be2 = be2b + (size_t)gl*H;
  const float* Wx = Wxb + (size_t)gl*H;

  int lane = tid & 63, wave = tid >> 6;
  int c = lane & 15, q = lane >> 4;

  // wave-private preamble: indices + rel/d2 for this wave's 32 edges (no barrier)
  if (lane < 32){
    int e = wave*32 + lane;
    int s = ssrc[e0+e], d = sdst[e0+e];
    sI[e] = s; dI[e] = d;
    float rx = x[d*3+0]-x[s*3+0];
    float ry = x[d*3+1]-x[s*3+1];
    float rz = x[d*3+2]-x[s*3+2];
    relS[e][0]=rx; relS[e][1]=ry; relS[e][2]=rz;
    d2S[e] = rx*rx+ry*ry+rz*rz;
  }

  int eA = wave*32 + c;          // tile0 A-row
  int eB = eA + 16;              // tile1 A-row
  const unsigned short* pD0 = hb + (size_t)dI[eA]*H + q*8;
  const unsigned short* pS0 = hb + (size_t)sI[eA]*H + q*8;
  const unsigned short* pD1 = hb + (size_t)dI[eB]*H + q*8;
  const unsigned short* pS1 = hb + (size_t)sI[eB]*H + q*8;

  // full A-frag prefetch, both tiles (16 x s8)
  s8 af0[8], af1[8];
  #pragma unroll
  for (int ks=0; ks<4; ks++){
    af0[ks]   = *(const s8*)(pD0 + ks*32);
    af0[4+ks] = *(const s8*)(pS0 + ks*32);
    af1[ks]   = *(const s8*)(pD1 + ks*32);
    af1[4+ks] = *(const s8*)(pS1 + ks*32);
  }

  // ---- GEMM1 (K=256), B loaded once per (ks,t), feeds both tiles ----
  f32x4 acc0[8], acc1[8];
  #pragma unroll
  for (int t=0;t<8;t++){ acc0[t] = (f32x4){0.f,0.f,0.f,0.f}; acc1[t] = (f32x4){0.f,0.f,0.f,0.f}; }
  const s8* B1 = (const s8*)We1p;
  #pragma unroll
  for (int ks=0; ks<8; ks++){
    const s8* bp = B1 + (ks*8)*64 + lane;
    #pragma unroll
    for (int t=0;t<8;t++){
      s8 B = bp[t*64];
      acc0[t] = __builtin_amdgcn_mfma_f32_16x16x32_bf16(af0[ks], B, acc0[t], 0,0,0);
      acc1[t] = __builtin_amdgcn_mfma_f32_16x16x32_bf16(af1[ks], B, acc1[t], 0,0,0);
    }
  }

  int er0 = wave*32 + 4*q;
  int er1 = er0 + 16;
  float d20[4], d21[4];
  #pragma unroll
  for (int i=0;i<4;i++){ d20[i] = d2S[er0+i]; d21[i] = d2S[er1+i]; }
  #pragma unroll
  for (int t=0;t<8;t++){
    int j2 = 16*t + c;
    float w256 = We1r256[j2], bias = be1[j2];
    s4 mv0, mv1;
    #pragma unroll
    for (int i=0;i<4;i++){
      mv0[i] = (short)f2bf(silu_f(acc0[t][i] + d20[i]*w256 + bias));
      mv1[i] = (short)f2bf(silu_f(acc1[t][i] + d21[i]*w256 + bias));
    }
    *(s4*)&m_lds[136*j2 + er0] = mv0;   // wave-private edge columns
    *(s4*)&m_lds[136*j2 + er1] = mv1;
  }

  // ---- GEMM2 (K=128), wave-private m_lds reads, B shared across tiles ----
  #pragma unroll
  for (int t=0;t<8;t++){ acc0[t] = (f32x4){0.f,0.f,0.f,0.f}; acc1[t] = (f32x4){0.f,0.f,0.f,0.f}; }
  const s8* B2 = (const s8*)We2p;
  #pragma unroll
  for (int ks=0; ks<4; ks++){
    s8 a20, a21;
    int base = 136*(32*ks + 8*q) + wave*32 + c;
    #pragma unroll
    for (int j=0;j<8;j++){
      a20[j] = (short)m_lds[base + 136*j];
      a21[j] = (short)m_lds[base + 16 + 136*j];
    }
    const s8* bp = B2 + (ks*8)*64 + lane;
    #pragma unroll
    for (int t=0;t<8;t++){
      s8 B = bp[t*64];
      acc0[t] = __builtin_amdgcn_mfma_f32_16x16x32_bf16(a20, B, acc0[t], 0,0,0);
      acc1[t] = __builtin_amdgcn_mfma_f32_16x16x32_bf16(a21, B, acc1[t], 0,0,0);
    }
  }
  __syncthreads();   // ONLY barrier: m_lds (all waves' reads) -> m2t overlay (cross-wave clobber)

  // epilogue: silu + coef partials; m2 bf16 into transpose LDS (row-major [e][136])
  float pp0[4] = {0.f,0.f,0.f,0.f};
  float pp1[4] = {0.f,0.f,0.f,0.f};
  #pragma unroll
  for (int t=0;t<8;t++){
    int j2 = 16*t + c;
    float b2v = be2[j2], wxv = Wx[j2];
    #pragma unroll
    for (int i=0;i<4;i++){
      float v0 = silu_f(acc0[t][i] + b2v);
      float v1 = silu_f(acc1[t][i] + b2v);
      pp0[i] += v0*wxv;
      pp1[i] += v1*wxv;
      m2t[(er0+i)*136 + j2] = f2bf(v0);
      m2t[(er1+i)*136 + j2] = f2bf(v1);
    }
  }
  #pragma unroll
  for (int off=1; off<16; off<<=1){
    #pragma unroll
    for (int i=0;i<4;i++){
      pp0[i] += __shfl_xor(pp0[i], off, 64);
      pp1[i] += __shfl_xor(pp1[i], off, 64);
    }
  }
  if (c == 0){
    float bxv = bxb[gl];
    #pragma unroll
    for (int i=0;i<4;i++){
      int e = er0 + i;
      float cf = pp0[i] + bxv;
      float* rp = relcf + (size_t)(e0+e)*3;
      rp[0] = relS[e][0]*cf; rp[1] = relS[e][1]*cf; rp[2] = relS[e][2]*cf;
      e = er1 + i;
      cf = pp1[i] + bxv;
      rp = relcf + (size_t)(e0+e)*3;
      rp[0] = relS[e][0]*cf; rp[1] = relS[e][1]*cf; rp[2] = relS[e][2]*cf;
    }
  }

  // coalesced m2 store: lane -> (own wave's edge, 64-col half); wave-private m2t rows
  {
    int e = wave*32 + (lane >> 1), cb = (lane & 1) * 64;
    const s8* sp = (const s8*)&m2t[e*136 + cb];
    s8* dp = (s8*)(m2e + (size_t)(e0+e)*H + cb);
    #pragma unroll
    for (int s2=0; s2<8; s2++) dp[s2] = sp[s2];
  }
}

// ---------------- fused node update: CSR reduce + bf16 MFMA, barrier-free ----------------
__global__ __launch_bounds__(128, 4) void k_node_f(
    float* __restrict__ h_l, unsigned short* __restrict__ hb_l, float* __restrict__ x_l,
    float* __restrict__ h_p, unsigned short* __restrict__ hb_p, float* __restrict__ x_p,
    const unsigned short* __restrict__ m2e_l, const float* __restrict__ relcf_l,
    const unsigned short* __restrict__ m2e_p, const float* __restrict__ relcf_p,
    const int* __restrict__ offs_l, const int* __restrict__ offs_p,
    const unsigned short* __restrict__ Wh1pb, const float* __restrict__ bh1b,
    const unsigned short* __restrict__ Wh2pb, const float* __restrict__ bh2b,
    int layer)
{
  __shared__ __align__(16) unsigned short aggS[32*136];   // agg_m bf16, [node][col] stride 136
  __shared__ __align__(16) unsigned short u_lds[128*36];
  __shared__ float rcS[32][3];
  __shared__ int degS[32];

  int tid = threadIdx.x;
  int bid = xcd_swz(blockIdx.x, NBLK_NL + NBLK_NP);
  int g = (bid < NBLK_NL) ? 0 : 1;
  int nb0 = (g ? bid - NBLK_NL : bid) * 32;
  int N = g ? NPOC : NLIG;
  float* h = g ? h_p : h_l;
  unsigned short* hbm = g ? hb_p : hb_l;
  float* x = g ? x_p : x_l;
  const unsigned short* m2e = g ? m2e_p : m2e_l;
  const float* relcf = g ? relcf_p : relcf_l;
  const int* offs = g ? offs_p : offs_l;
  int gl = g*NLAYERS + layer;
  const unsigned short* Wh1p = Wh1pb + (size_t)gl*G1S;
  const unsigned short* Wh2p = Wh2pb + (size_t)gl*G2S;
  const float* bh1 = bh1b + (size_t)gl*H;
  const float* bh2 = bh2b + (size_t)gl*H;

  int lane = tid & 63, wave = tid >> 6;

  // ---- phase A: CSR reduce; wave w owns nodes [w*16, w*16+16) (wave-private) ----
  {
    int nloc = tid >> 2, cb = (tid & 3) * 32;   // wave0 -> nloc 0..15, wave1 -> 16..31
    int gn = nb0 + nloc;
    int gna = (gn < N) ? gn : (N-1);
    int o0 = offs[gna], o1 = offs[gna+1];
    float sums[32];
    #pragma unroll
    for (int k=0;k<32;k++) sums[k] = 0.f;
    float rc0=0.f, rc1=0.f, rc2=0.f;
    bool rc_owner = (tid & 3) == 0;
    for (int e = o0; e < o1; e++){
      const unsigned short* mp = m2e + (size_t)e*H + cb;
      #pragma unroll
      for (int s2=0; s2<4; s2++){
        s8 v = *(const s8*)(mp + s2*8);
        #pragma unroll
        for (int j=0;j<8;j++)
          sums[s2*8+j] += bf2f((unsigned short)v[j]);
      }
      if (rc_owner){
        const float* rp = relcf + (size_t)e*3;
        rc0 += rp[0]; rc1 += rp[1]; rc2 += rp[2];
      }
    }
    unsigned short* ap = &aggS[nloc*136 + cb];
    #pragma unroll
    for (int s2=0; s2<4; s2++){
      s8 vv;
      #pragma unroll
      for (int j=0;j<8;j++) vv[j] = (short)f2bf(sums[s2*8+j]);
      *(s8*)(ap + s2*8) = vv;
    }
    if (rc_owner){
      rcS[nloc][0] = rc0; rcS[nloc][1] = rc1; rcS[nloc][2] = rc2;
      degS[nloc] = o1 - o0;
    }
  }

  // x update: wave-aligned (wave w -> its own nodes), no barrier needed
  if (lane < 48){
    int nn = wave*16 + lane/3, cc = lane - (lane/3)*3;
    int gn = nb0 + nn;
    if (gn < N){
      float dv = (float)degS[nn]; if (dv < 1.f) dv = 1.f;
      x[(size_t)gn*3 + cc] += rcS[nn][cc] / dv;
    }
  }

  int c = lane & 15, q = lane >> 4;
  int node = nb0 + wave*16 + c;
  int na = node < N ? node : N-1;
  int nloc2 = wave*16 + c;

  // A frags: ks 0..3 = h (bf16 mirror), ks 4..7 = aggS (bf16, wave-private rows)
  s8 af[8];
  #pragma unroll
  for (int ks=0; ks<4; ks++)
    af[ks] = *(const s8*)(hbm + (size_t)na*H + ks*32 + q*8);
  #pragma unroll
  for (int ks=4; ks<8; ks++)
    af[ks] = *(const s8*)&aggS[nloc2*136 + (ks-4)*32 + q*8];

  f32x4 acc[8];
  #pragma unroll
  for (int t=0;t<8;t++) acc[t] = (f32x4){0.f,0.f,0.f,0.f};
  const s8* B1 = (const s8*)Wh1p;
  #pragma unroll
  for (int ks=0; ks<8; ks++){
    const s8* bp = B1 + (ks*8)*64 + lane;
    #pragma unroll
    for (int t=0;t<8;t++)
      acc[t] = __builtin_amdgcn_mfma_f32_16x16x32_bf16(af[ks], bp[t*64], acc[t], 0,0,0);
  }

  int er0 = wave*16 + 4*q;
  #pragma unroll
  for (int t=0;t<8;t++){
    int j2 = 16*t + c;
    float b1 = bh1[j2];
    s4 mv;
    #pragma unroll
    for (int i=0;i<4;i++) mv[i] = (short)f2bf(silu_f(acc[t][i] + b1));
    *(s4*)&u_lds[36*j2 + er0] = mv;   // wave-private rows
  }

  f32x4 acc2[8];
  #pragma unroll
  for (int t=0;t<8;t++) acc2[t] = (f32x4){0.f,0.f,0.f,0.f};
  const s8* B2 = (const s8*)Wh2p;
  #pragma unroll
  for (int ks=0; ks<4; ks++){
    s8 a2;
    int base = 36*(32*ks + 8*q) + wave*16 + c;
    #pragma unroll
    for (int j=0;j<8;j++) a2[j] = (short)u_lds[base + 36*j];
    const s8* bp = B2 + (ks*8)*64 + lane;
    #pragma unroll
    for (int t=0;t<8;t++)
      acc2[t] = __builtin_amdgcn_mfma_f32_16x16x32_bf16(a2, bp[t*64], acc2[t], 0,0,0);
  }

  #pragma unroll
  for (int t=0;t<8;t++){
    int j2 = 16*t + c;
    float b2 = bh2[j2];
    #pragma unroll
    for (int i=0;i<4;i++){
      int gr = nb0 + wave*16 + 4*q + i;
      if (gr < N){
        size_t off = (size_t)gr*H + j2;
        float hv = h[off] + acc2[t][i] + b2;
        h[off] = hv;
        hbm[off] = f2bf(hv);
      }
    }
  }
}

// ---------------- NextType head via bf16 MFMA, 8 waves, f-parallel ----------------
__global__ __launch_bounds__(512, 2) void k_head3(
    const unsigned short* __restrict__ hb, const int* __restrict__ batch,
    const unsigned short* __restrict__ W1p, const float* __restrict__ bd1,
    const unsigned short* __restrict__ Wd2p, const float* __restrict__ bd2,
    const float* __restrict__ Wd3, const float* __restrict__ bd3,
    float* __restrict__ agg, int N)
{
  __shared__ __align__(16) unsigned short t1tr[96*132];
  __shared__ float t3s[32][18];
  __shared__ float lgs[32][18];
  __shared__ int bI[32];

  int tid = threadIdx.x;
  int nb0 = blockIdx.x * 32;
  int lane = tid & 63, wave = tid >> 6;
  int pair = wave >> 1, sub = wave & 1;
  int c = lane & 15, q = lane >> 4;

  int node = nb0 + sub*16 + c;
  int na = node < N ? node : N-1;

  s8 ah[4];
  #pragma unroll
  for (int ks=0; ks<4; ks++)
    ah[ks] = *(const s8*)(hb + (size_t)na*H + ks*32 + q*8);

  float b1c[6];
  #pragma unroll
  for (int t=0;t<6;t++){ int col=16*t+c; b1c[t] = (col<85) ? bd1[col] : 0.f; }
  float b2c[3], w3c[3];
  #pragma unroll
  for (int t=0;t<3;t++){
    int col=16*t+c;
    b2c[t] = (col<43) ? bd2[col] : 0.f;
    w3c[t] = (col<43) ? Wd3[col] : 0.f;
  }
  float bd3v = bd3[0];
  int rbase = wave*16;
  int er0 = rbase + 4*q;

  for (int fi=0; fi<4; fi++){
    int f = pair + 4*fi;
    const s8* B1 = (const s8*)W1p + f*(W1FS/8);
    f32x4 acc[6];
    #pragma unroll
    for (int t=0;t<6;t++) acc[t] = (f32x4){0.f,0.f,0.f,0.f};
    #pragma unroll
    for (int ks=0; ks<4; ks++){
      #pragma unroll
      for (int t=0;t<6;t++)
        acc[t] = __builtin_amdgcn_mfma_f32_16x16x32_bf16(ah[ks], B1[(ks*6+t)*64+lane], acc[t], 0,0,0);
    }
    #pragma unroll
    for (int t=0;t<6;t++){
      int j2 = 16*t + c;
      s4 mv;
      #pragma unroll
      for (int i=0;i<4;i++) mv[i] = (short)f2bf(silu_f(acc[t][i] + b1c[t]));
      *(s4*)&t1tr[132*j2 + er0] = mv;
    }
    f32x4 acc2[3];
    #pragma unroll
    for (int t=0;t<3;t++) acc2[t] = (f32x4){0.f,0.f,0.f,0.f};
    const s8* B2 = (const s8*)Wd2p;
    #pragma unroll
    for (int ks=0; ks<3; ks++){
      s8 a2;
      int base = 132*(32*ks + 8*q) + rbase + c;
      #pragma unroll
      for (int j=0;j<8;j++) a2[j] = (short)t1tr[base + 132*j];
      #pragma unroll
      for (int t=0;t<3;t++)
        acc2[t] = __builtin_amdgcn_mfma_f32_16x16x32_bf16(a2, B2[(ks*3+t)*64+lane], acc2[t], 0,0,0);
    }
    float pp[4] = {0.f,0.f,0.f,0.f};
    #pragma unroll
    for (int t=0;t<3;t++){
      #pragma unroll
      for (int i=0;i<4;i++) pp[i] += silu_f(acc2[t][i] + b2c[t]) * w3c[t];
    }
    #pragma unroll
    for (int off=1; off<16; off<<=1){
      #pragma unroll
      for (int i=0;i<4;i++) pp[i] += __shfl_xor(pp[i], off, 64);
    }
    if (c == 0){
      #pragma unroll
      for (int i=0;i<4;i++) t3s[sub*16 + 4*q + i][f] = pp[i] + bd3v;
    }
  }
  __syncthreads();

  if (tid < 32){
    int n = nb0 + tid;
    bool valid = n < N;
    bI[tid] = batch[valid ? n : (N-1)];
    if (valid){
      float m = t3s[tid][0];
      #pragma unroll
      for (int i=1;i<16;i++) m = fmaxf(m, t3s[tid][i]);
      float s = 0.f;
      #pragma unroll
      for (int i=0;i<16;i++) s += __expf(t3s[tid][i] - m);
      float ls = __logf(s);
      #pragma unroll
      for (int i=0;i<16;i++) lgs[tid][i] = t3s[tid][i] - m - ls;
    } else {
      #pragma unroll
      for (int i=0;i<16;i++) lgs[tid][i] = 0.f;
    }
  }
  __syncthreads();

  if (tid < 16){
    int f = tid;
    float acc = 0.f; int run = bI[0];
    for (int n = 0; n < 32; n++){
      int b = bI[n];
      if (b != run){ atomicAdd(&agg[run*16 + f], acc); acc = 0.f; run = b; }
      acc += lgs[n][f];
    }
    atomicAdd(&agg[run*16 + f], acc);
  }
}

// ---------------- final: out = agg - logsumexp(agg) ----------------
__global__ void k_final(const float* __restrict__ agg, float* __restrict__ out){
  int tid = threadIdx.x;
  float vv = agg[tid];
  float m = vv;
  #pragma unroll
  for (int off = 1; off < 16; off <<= 1) m = fmaxf(m, __shfl_xor(m, off, 64));
  float s = __expf(vv - m);
  #pragma unroll
  for (int off = 1; off < 16; off <<= 1) s += __shfl_xor(s, off, 64);
  out[tid] = vv - m - __logf(s);
}

extern "C" void kernel_launch(void* const* d_in, const int* in_sizes, int n_in,
                              void* d_out, int out_size, void* d_ws, size_t ws_size,
                              hipStream_t stream)
{
  const float* ligand_x   = (const float*)d_in[0];
  const float* pocket_x   = (const float*)d_in[1];
  const float* ligand_pos = (const float*)d_in[2];
  const float* pocket_pos = (const float*)d_in[3];
  const float* Wl_emb = (const float*)d_in[4];
  const float* bl_emb = (const float*)d_in[5];
  const float* Wp_emb = (const float*)d_in[6];
  const float* bp_emb = (const float*)d_in[7];
  const float* We1 = (const float*)d_in[8];
  const float* be1 = (const float*)d_in[9];
  const float* We2 = (const float*)d_in[10];
  const float* be2 = (const float*)d_in[11];
  const float* Wx  = (const float*)d_in[12];
  const float* bx  = (const float*)d_in[13];
  const float* Wh1 = (const float*)d_in[14];
  const float* bh1 = (const float*)d_in[15];
  const float* Wh2 = (const float*)d_in[16];
  const float* bh2 = (const float*)d_in[17];
  const float* Wd1 = (const float*)d_in[18];
  const float* bd1 = (const float*)d_in[19];
  const float* Wd2 = (const float*)d_in[20];
  const float* bd2 = (const float*)d_in[21];
  const float* Wd3 = (const float*)d_in[22];
  const float* bd3 = (const float*)d_in[23];
  const int* l2l    = (const int*)d_in[24];
  const int* p2p    = (const int*)d_in[25];
  const int* lbatch = (const int*)d_in[26];

  char* w = (char*)d_ws;
  auto alloc = [&](size_t bytes)->char*{
    char* p = w; w += (bytes + 255) & ~(size_t)255; return p;
  };
  float* hl    = (float*)alloc((size_t)NLIG*H*4);
  float* hp    = (float*)alloc((size_t)NPOC*H*4);
  unsigned short* hbl = (unsigned short*)alloc((size_t)NLIG*H*2);
  unsigned short* hbp = (unsigned short*)alloc((size_t)NPOC*H*2);
  float* xl    = (float*)alloc((size_t)NLIG*3*4);
  float* xp    = (float*)alloc((size_t)NPOC*3*4);
  int* offs_l = (int*)alloc((size_t)(NLIG+1)*4);
  int* offs_p = (int*)alloc((size_t)(NPOC+1)*4);
  int* ssrc_l = (int*)alloc((size_t)ELIG*4);
  int* sdst_l = (int*)alloc((size_t)ELIG*4);
  int* ssrc_p = (int*)alloc((size_t)EPOC*4);
  int* sdst_p = (int*)alloc((size_t)EPOC*4);
  unsigned short* We1p = (unsigned short*)alloc((size_t)6*G1S*2);
  unsigned short* We2p = (unsigned short*)alloc((size_t)6*G2S*2);
  unsigned short* Wh1p = (unsigned short*)alloc((size_t)6*G1S*2);
  unsigned short* Wh2p = (unsigned short*)alloc((size_t)6*G2S*2);
  unsigned short* W1p  = (unsigned short*)alloc((size_t)16*W1FS*2);
  unsigned short* Wd2p = (unsigned short*)alloc((size_t)WD2S*2);
  unsigned short* m2e_l = (unsigned short*)alloc((size_t)ELIG*H*2);
  unsigned short* m2e_p = (unsigned short*)alloc((size_t)EPOC*H*2);
  float* relcf_l = (float*)alloc((size_t)ELIG*3*4);
  float* relcf_p = (float*)alloc((size_t)EPOC*3*4);
  // ---- contiguous zero-init region ----
  char* zbase = w;
  int* deg_l = (int*)alloc((size_t)NLIG*4);
  int* deg_p = (int*)alloc((size_t)NPOC*4);
  int* cur_l = (int*)alloc((size_t)NLIG*4);
  int* cur_p = (int*)alloc((size_t)NPOC*4);
  float* aggB = (float*)alloc((size_t)NB*16*4);
  size_t zsize = (size_t)(w - zbase);

  hipMemsetAsync(zbase, 0, zsize, stream);

  const int* lsrc = l2l;          const int* ldst = l2l + ELIG;
  const int* psrc = p2p;          const int* pdst = p2p + EPOC;

  k_embed2<<<NLIG/2 + NPOC/2, 256, 0, stream>>>(ligand_x, pocket_x, ligand_pos, pocket_pos,
      Wl_emb, bl_emb, Wp_emb, bp_emb, hl, hbl, hp, hbp, xl, xp);
  k_hist2<<<(ELIG+EPOC+255)/256, 256, 0, stream>>>(ldst, pdst, deg_l, deg_p);
  k_scan2<<<2, 1024, 0, stream>>>(deg_l, offs_l, deg_p, offs_p);
  k_sort2<<<(ELIG+EPOC+255)/256, 256, 0, stream>>>(lsrc, ldst, psrc, pdst,
      offs_l, offs_p, cur_l, cur_p, ssrc_l, sdst_l, ssrc_p, sdst_p);
  {
    int npack = 6*G1S + 6*G2S + 6*G1S + 6*G2S + 16*W1FS + WD2S;
    k_pack<<<(npack+255)/256, 256, 0, stream>>>(We1, We2, Wh1, Wh2,
        Wl_emb, bl_emb, Wd1, Wd2, We1p, We2p, Wh1p, Wh2p, W1p, Wd2p);
  }

  for (int l = 0; l < NLAYERS; l++){
    k_edge_f<<<NBLK_EL + NBLK_EP, 256, 0, stream>>>(hbl, hbp, xl, xp,
        ssrc_l, sdst_l, ssrc_p, sdst_p,
        We1p, We1, be1, We2p, be2, Wx, bx,
        m2e_l, relcf_l, m2e_p, relcf_p, l);
    k_node_f<<<NBLK_NL + NBLK_NP, 128, 0, stream>>>(hl, hbl, xl, hp, hbp, xp,
        m2e_l, relcf_l, m2e_p, relcf_p, offs_l, offs_p,
        Wh1p, bh1, Wh2p, bh2, l);
  }

  k_head3<<<(NLIG+31)/32, 512, 0, stream>>>(hbl, lbatch, W1p, bd1, Wd2p, bd2,
                                            Wd3, bd3, aggB, NLIG);
  k_final<<<1, 128, 0, stream>>>(aggB, (float*)d_out);
}

// Round 15
// 647.074 us; speedup vs baseline: 2.2898x; 1.0139x over previous
//
#include <hip/hip_runtime.h>
#include <hip/hip_bf16.h>
#include <math.h>

typedef __attribute__((ext_vector_type(4))) float f4;
typedef __attribute__((ext_vector_type(4))) float f32x4;
typedef __attribute__((ext_vector_type(8))) short s8;
typedef __attribute__((ext_vector_type(4))) short s4;

#define H 128
#define NLAYERS 3
#define FLIG 16
#define FPOC 27
#define NLIG 20000
#define NPOC 30000
#define ELIG 160000
#define EPOC 240000
#define NB 8

#define EPB 128                  // edges per block
#define NBLK_EL (ELIG/EPB)       // 1250
#define NBLK_EP (EPOC/EPB)       // 1875
#define NBLK_NL ((NLIG+31)/32)   // 625
#define NBLK_NP ((NPOC+31)/32)   // 938

// packed-weight strides (elements)
#define G1S (8*8*64*8)   // K=256 GEMM1 weights per group (8 ksteps x 8 coltiles)
#define G2S (4*8*64*8)   // K=128 GEMM2 weights per group
#define W1FS (4*6*64*8)  // head W1f per f: 4 ksteps x 6 coltiles
#define WD2S (3*3*64*8)  // head Wd2: 3 ksteps x 3 coltiles

// silu with hw rcp (rel err ~1e-5, far below bf16 eps)
__device__ __forceinline__ float silu_f(float v){
  return v * __builtin_amdgcn_rcpf(1.0f + __expf(-v));
}
__device__ __forceinline__ unsigned short f2bf(float v){
  __hip_bfloat16 b = __float2bfloat16(v);
  return *reinterpret_cast<unsigned short*>(&b);
}
__device__ __forceinline__ float bf2f(unsigned short u){
  unsigned int x = ((unsigned int)u) << 16;
  return __uint_as_float(x);
}
// bijective XCD-chunked swizzle
__device__ __forceinline__ int xcd_swz(int bid, int nwg){
  int q = nwg >> 3, r = nwg & 7;
  int x = bid & 7, w = bid >> 3;
  return (x < r) ? (x*(q+1) + w) : (r*(q+1) + (x-r)*q + w);
}

// ---------------- fused embedding (both graphs) + position copy ----------------
__global__ void k_embed2(const float* __restrict__ lx, const float* __restrict__ px,
                         const float* __restrict__ lpos, const float* __restrict__ ppos,
                         const float* __restrict__ Wl, const float* __restrict__ bl,
                         const float* __restrict__ Wp, const float* __restrict__ bp,
                         float* __restrict__ hl, unsigned short* __restrict__ hbl,
                         float* __restrict__ hp, unsigned short* __restrict__ hbp,
                         float* __restrict__ xl, float* __restrict__ xp){
  int bid = blockIdx.x;
  int g = (bid < NLIG/2) ? 0 : 1;
  int nb = (g ? bid - NLIG/2 : bid) * 2;
  const float* x  = g ? px : lx;
  const float* W  = g ? Wp : Wl;
  const float* b  = g ? bp : bl;
  float* h = g ? hp : hl;
  unsigned short* hb = g ? hbp : hbl;
  int F = g ? FPOC : FLIG;
  int tid = threadIdx.x;
  int n = nb + (tid >> 7);
  int j = tid & 127;
  float acc = b[j];
  for (int k = 0; k < F; k++) acc += x[n*F + k] * W[k*H + j];
  h[(size_t)n*H + j] = acc;
  hb[(size_t)n*H + j] = f2bf(acc);
  if (tid < 6){
    const float* pos = g ? ppos : lpos;
    float* xd = g ? xp : xl;
    xd[(size_t)nb*3 + tid] = pos[(size_t)nb*3 + tid];
  }
}

// ---------------- fused degree histogram ----------------
__global__ void k_hist2(const int* __restrict__ ldst, const int* __restrict__ pdst,
                        int* __restrict__ deg_l, int* __restrict__ deg_p){
  int e = blockIdx.x*256 + threadIdx.x;
  if (e < ELIG) atomicAdd(&deg_l[ldst[e]], 1);
  else if (e < ELIG+EPOC) atomicAdd(&deg_p[pdst[e-ELIG]], 1);
}

// ---------------- both exclusive scans, one dispatch ----------------
__global__ void k_scan2(const int* __restrict__ deg_l, int* __restrict__ offs_l,
                        const int* __restrict__ deg_p, int* __restrict__ offs_p){
  __shared__ int part[1024];
  const int* deg = blockIdx.x ? deg_p : deg_l;
  int* offs = blockIdx.x ? offs_p : offs_l;
  int N = blockIdx.x ? NPOC : NLIG;
  int E = blockIdx.x ? EPOC : ELIG;
  int t = threadIdx.x;
  int chunk = (N + 1023) >> 10;
  int b0 = t*chunk;
  int b1 = b0 + chunk; if (b1 > N) b1 = N;
  int s = 0;
  for (int i = b0; i < b1; i++) s += deg[i];
  part[t] = s;
  __syncthreads();
  for (int off = 1; off < 1024; off <<= 1){
    int v = (t >= off) ? part[t-off] : 0;
    __syncthreads();
    part[t] += v;
    __syncthreads();
  }
  int run = part[t] - s;
  for (int i = b0; i < b1; i++){ offs[i] = run; run += deg[i]; }
  if (t == 1023) offs[N] = E;
}

// ---------------- fused counting-sort scatter ----------------
__global__ void k_sort2(const int* __restrict__ lsrc, const int* __restrict__ ldst,
                        const int* __restrict__ psrc, const int* __restrict__ pdst,
                        const int* __restrict__ offs_l, const int* __restrict__ offs_p,
                        int* __restrict__ cur_l, int* __restrict__ cur_p,
                        int* __restrict__ ssrc_l, int* __restrict__ sdst_l,
                        int* __restrict__ ssrc_p, int* __restrict__ sdst_p){
  int e = blockIdx.x*256 + threadIdx.x;
  if (e < ELIG){
    int d = ldst[e];
    int p = offs_l[d] + atomicAdd(&cur_l[d], 1);
    ssrc_l[p] = lsrc[e]; sdst_l[p] = d;
  } else if (e < ELIG+EPOC){
    int ee = e - ELIG;
    int d = pdst[ee];
    int p = offs_p[d] + atomicAdd(&cur_p[d], 1);
    ssrc_p[p] = psrc[ee]; sdst_p[p] = d;
  }
}

// ---------------- weight packer: MFMA fragment order, fp32 -> bf16 ----------------
__global__ void k_pack(const float* __restrict__ We1, const float* __restrict__ We2,
                       const float* __restrict__ Wh1, const float* __restrict__ Wh2,
                       const float* __restrict__ Wl, const float* __restrict__ bl,
                       const float* __restrict__ Wd1, const float* __restrict__ Wd2,
                       unsigned short* __restrict__ We1p, unsigned short* __restrict__ We2p,
                       unsigned short* __restrict__ Wh1p, unsigned short* __restrict__ Wh2p,
                       unsigned short* __restrict__ W1p, unsigned short* __restrict__ Wd2p)
{
  int idx = blockIdx.x*256 + threadIdx.x;
  const int nWe1 = 6*G1S, nWe2 = 6*G2S, nWh1 = 6*G1S, nWh2 = 6*G2S, nW1 = 16*W1FS, nWd2 = WD2S;
  int i = idx;
  if (i < nWe1){
    int j = i&7, l = (i>>3)&63, t = (i>>9)&7, ks = (i>>12)&7, g = i>>15;
    int k = 32*ks + 8*(l>>4) + j, col = 16*t + (l&15);
    We1p[i] = f2bf(We1[((size_t)g*257 + k)*H + col]);
    return;
  }
  i -= nWe1;
  if (i < nWe2){
    int j = i&7, l = (i>>3)&63, t = (i>>9)&7, ks = (i>>12)&3, g = i>>14;
    int k = 32*ks + 8*(l>>4) + j, col = 16*t + (l&15);
    We2p[i] = f2bf(We2[((size_t)g*H + k)*H + col]);
    return;
  }
  i -= nWe2;
  if (i < nWh1){
    int j = i&7, l = (i>>3)&63, t = (i>>9)&7, ks = (i>>12)&7, g = i>>15;
    int k = 32*ks + 8*(l>>4) + j, col = 16*t + (l&15);
    Wh1p[i] = f2bf(Wh1[((size_t)g*256 + k)*H + col]);
    return;
  }
  i -= nWh1;
  if (i < nWh2){
    int j = i&7, l = (i>>3)&63, t = (i>>9)&7, ks = (i>>12)&3, g = i>>14;
    int k = 32*ks + 8*(l>>4) + j, col = 16*t + (l&15);
    Wh2p[i] = f2bf(Wh2[((size_t)g*H + k)*H + col]);
    return;
  }
  i -= nWh2;
  if (i < nW1){
    int f = i / W1FS, r = i % W1FS;
    int ks = r / (6*512), r2 = r % (6*512);
    int t = r2 / 512, l = (r2 % 512) >> 3, j = r2 & 7;
    int k = 32*ks + 8*(l>>4) + j, col = 16*t + (l&15);
    float v = 0.f;
    if (col < 85) v = (Wl[f*H + k] + bl[k]) * Wd1[k*85 + col];
    W1p[i] = f2bf(v);
    return;
  }
  i -= nW1;
  if (i < nWd2){
    int ks = i / (3*512), r2 = i % (3*512);
    int t = r2 / 512, l = (r2 % 512) >> 3, j = r2 & 7;
    int k = 32*ks + 8*(l>>4) + j, col = 16*t + (l&15);
    float v = 0.f;
    if (k < 85 && col < 43) v = Wd2[k*43 + col];
    Wd2p[i] = f2bf(v);
  }
}

// ---------------- fused edge MLP (bf16 MFMA), 128 edges/block, 2 tiles/wave ----------------
// Staged A-frags (dst half then src half reusing regs) -> peak ~100 regs -> 4 blocks/CU.
__global__ __launch_bounds__(256, 4) void k_edge_f(
    const unsigned short* __restrict__ hb_l, const unsigned short* __restrict__ hb_p,
    const float* __restrict__ x_l, const float* __restrict__ x_p,
    const int* __restrict__ ssrc_l, const int* __restrict__ sdst_l,
    const int* __restrict__ ssrc_p, const int* __restrict__ sdst_p,
    const unsigned short* __restrict__ We1pb, const float* __restrict__ We1b,
    const float* __restrict__ be1b,
    const unsigned short* __restrict__ We2pb, const float* __restrict__ be2b,
    const float* __restrict__ Wxb, const float* __restrict__ bxb,
    unsigned short* __restrict__ m2e_l, float* __restrict__ relcf_l,
    unsigned short* __restrict__ m2e_p, float* __restrict__ relcf_p,
    int layer)
{
  __shared__ __align__(16) unsigned short m_lds[128*136]; // col-major [k][edge] s=136; overlay m2t [e][136]
  __shared__ float relS[128][3];
  __shared__ float d2S[128];
  __shared__ int sI[128], dI[128];
  unsigned short* m2t = m_lds;

  int tid = threadIdx.x;
  int bid = xcd_swz(blockIdx.x, NBLK_EL + NBLK_EP);
  int g = (bid < NBLK_EL) ? 0 : 1;
  int e0 = (g ? bid - NBLK_EL : bid) * EPB;
  const unsigned short* hb = g ? hb_p : hb_l;
  const float* x = g ? x_p : x_l;
  const int* ssrc = g ? ssrc_p : ssrc_l;
  const int* sdst = g ? sdst_p : sdst_l;
  unsigned short* m2e = g ? m2e_p : m2e_l;
  float* relcf = g ? relcf_p : relcf_l;
  int gl = g*NLAYERS + layer;
  const unsigned short* We1p = We1pb + (size_t)gl*G1S;
  const unsigned short* We2p = We2pb + (size_t)gl*G2S;
  const float* We1r256 = We1b + ((size_t)gl*257 + 256)*H;
  const float* be1 = be1b + (size_t)gl*H;
  const float* be2 = be2b + (size_t)gl*H;
  const float* Wx = Wxb + (size_t)gl*H;

  int lane = tid & 63, wave = tid >> 6;
  int c = lane & 15, q = lane >> 4;

  // wave-private preamble: indices + rel/d2 for this wave's 32 edges (no barrier)
  if (lane < 32){
    int e = wave*32 + lane;
    int s = ssrc[e0+e], d = sdst[e0+e];
    sI[e] = s; dI[e] = d;
    float rx = x[d*3+0]-x[s*3+0];
    float ry = x[d*3+1]-x[s*3+1];
    float rz = x[d*3+2]-x[s*3+2];
    relS[e][0]=rx; relS[e][1]=ry; relS[e][2]=rz;
    d2S[e] = rx*rx+ry*ry+rz*rz;
  }

  int eA = wave*32 + c;          // tile0 A-row
  int eB = eA + 16;              // tile1 A-row
  const unsigned short* pD0 = hb + (size_t)dI[eA]*H + q*8;
  const unsigned short* pS0 = hb + (size_t)sI[eA]*H + q*8;
  const unsigned short* pD1 = hb + (size_t)dI[eB]*H + q*8;
  const unsigned short* pS1 = hb + (size_t)sI[eB]*H + q*8;

  // ---- GEMM1 (K=256): staged A-frags (dst half, then src half reusing regs) ----
  f32x4 acc0[8], acc1[8];
  #pragma unroll
  for (int t=0;t<8;t++){ acc0[t] = (f32x4){0.f,0.f,0.f,0.f}; acc1[t] = (f32x4){0.f,0.f,0.f,0.f}; }
  const s8* B1 = (const s8*)We1p;

  s8 af0[4], af1[4];
  #pragma unroll
  for (int ks=0; ks<4; ks++){
    af0[ks] = *(const s8*)(pD0 + ks*32);
    af1[ks] = *(const s8*)(pD1 + ks*32);
  }
  #pragma unroll
  for (int ks=0; ks<4; ks++){
    const s8* bp = B1 + (ks*8)*64 + lane;
    #pragma unroll
    for (int t=0;t<8;t++){
      s8 B = bp[t*64];
      acc0[t] = __builtin_amdgcn_mfma_f32_16x16x32_bf16(af0[ks], B, acc0[t], 0,0,0);
      acc1[t] = __builtin_amdgcn_mfma_f32_16x16x32_bf16(af1[ks], B, acc1[t], 0,0,0);
    }
  }
  #pragma unroll
  for (int ks=0; ks<4; ks++){
    af0[ks] = *(const s8*)(pS0 + ks*32);
    af1[ks] = *(const s8*)(pS1 + ks*32);
  }
  #pragma unroll
  for (int ks=4; ks<8; ks++){
    const s8* bp = B1 + (ks*8)*64 + lane;
    #pragma unroll
    for (int t=0;t<8;t++){
      s8 B = bp[t*64];
      acc0[t] = __builtin_amdgcn_mfma_f32_16x16x32_bf16(af0[ks-4], B, acc0[t], 0,0,0);
      acc1[t] = __builtin_amdgcn_mfma_f32_16x16x32_bf16(af1[ks-4], B, acc1[t], 0,0,0);
    }
  }

  int er0 = wave*32 + 4*q;
  int er1 = er0 + 16;
  float d20[4], d21[4];
  #pragma unroll
  for (int i=0;i<4;i++){ d20[i] = d2S[er0+i]; d21[i] = d2S[er1+i]; }
  #pragma unroll
  for (int t=0;t<8;t++){
    int j2 = 16*t + c;
    float w256 = We1r256[j2], bias = be1[j2];
    s4 mv0, mv1;
    #pragma unroll
    for (int i=0;i<4;i++){
      mv0[i] = (short)f2bf(silu_f(acc0[t][i] + d20[i]*w256 + bias));
      mv1[i] = (short)f2bf(silu_f(acc1[t][i] + d21[i]*w256 + bias));
    }
    *(s4*)&m_lds[136*j2 + er0] = mv0;   // wave-private edge columns
    *(s4*)&m_lds[136*j2 + er1] = mv1;
  }

  // ---- GEMM2 (K=128), wave-private m_lds reads, B shared across tiles ----
  #pragma unroll
  for (int t=0;t<8;t++){ acc0[t] = (f32x4){0.f,0.f,0.f,0.f}; acc1[t] = (f32x4){0.f,0.f,0.f,0.f}; }
  const s8* B2 = (const s8*)We2p;
  #pragma unroll
  for (int ks=0; ks<4; ks++){
    s8 a20, a21;
    int base = 136*(32*ks + 8*q) + wave*32 + c;
    #pragma unroll
    for (int j=0;j<8;j++){
      a20[j] = (short)m_lds[base + 136*j];
      a21[j] = (short)m_lds[base + 16 + 136*j];
    }
    const s8* bp = B2 + (ks*8)*64 + lane;
    #pragma unroll
    for (int t=0;t<8;t++){
      s8 B = bp[t*64];
      acc0[t] = __builtin_amdgcn_mfma_f32_16x16x32_bf16(a20, B, acc0[t], 0,0,0);
      acc1[t] = __builtin_amdgcn_mfma_f32_16x16x32_bf16(a21, B, acc1[t], 0,0,0);
    }
  }
  __syncthreads();   // ONLY barrier: m_lds (all waves' reads) -> m2t overlay (cross-wave clobber)

  // epilogue: silu + coef partials; m2 bf16 into transpose LDS (row-major [e][136])
  float pp0[4] = {0.f,0.f,0.f,0.f};
  float pp1[4] = {0.f,0.f,0.f,0.f};
  #pragma unroll
  for (int t=0;t<8;t++){
    int j2 = 16*t + c;
    float b2v = be2[j2], wxv = Wx[j2];
    #pragma unroll
    for (int i=0;i<4;i++){
      float v0 = silu_f(acc0[t][i] + b2v);
      float v1 = silu_f(acc1[t][i] + b2v);
      pp0[i] += v0*wxv;
      pp1[i] += v1*wxv;
      m2t[(er0+i)*136 + j2] = f2bf(v0);
      m2t[(er1+i)*136 + j2] = f2bf(v1);
    }
  }
  #pragma unroll
  for (int off=1; off<16; off<<=1){
    #pragma unroll
    for (int i=0;i<4;i++){
      pp0[i] += __shfl_xor(pp0[i], off, 64);
      pp1[i] += __shfl_xor(pp1[i], off, 64);
    }
  }
  if (c == 0){
    float bxv = bxb[gl];
    #pragma unroll
    for (int i=0;i<4;i++){
      int e = er0 + i;
      float cf = pp0[i] + bxv;
      float* rp = relcf + (size_t)(e0+e)*3;
      rp[0] = relS[e][0]*cf; rp[1] = relS[e][1]*cf; rp[2] = relS[e][2]*cf;
      e = er1 + i;
      cf = pp1[i] + bxv;
      rp = relcf + (size_t)(e0+e)*3;
      rp[0] = relS[e][0]*cf; rp[1] = relS[e][1]*cf; rp[2] = relS[e][2]*cf;
    }
  }

  // coalesced m2 store: lane -> (own wave's edge, 64-col half); wave-private m2t rows
  {
    int e = wave*32 + (lane >> 1), cb = (lane & 1) * 64;
    const s8* sp = (const s8*)&m2t[e*136 + cb];
    s8* dp = (s8*)(m2e + (size_t)(e0+e)*H + cb);
    #pragma unroll
    for (int s2=0; s2<8; s2++) dp[s2] = sp[s2];
  }
}

// ---------------- fused node update: CSR reduce + bf16 MFMA, barrier-free ----------------
__global__ __launch_bounds__(128, 4) void k_node_f(
    float* __restrict__ h_l, unsigned short* __restrict__ hb_l, float* __restrict__ x_l,
    float* __restrict__ h_p, unsigned short* __restrict__ hb_p, float* __restrict__ x_p,
    const unsigned short* __restrict__ m2e_l, const float* __restrict__ relcf_l,
    const unsigned short* __restrict__ m2e_p, const float* __restrict__ relcf_p,
    const int* __restrict__ offs_l, const int* __restrict__ offs_p,
    const unsigned short* __restrict__ Wh1pb, const float* __restrict__ bh1b,
    const unsigned short* __restrict__ Wh2pb, const float* __restrict__ bh2b,
    int layer)
{
  __shared__ __align__(16) unsigned short aggS[32*136];   // agg_m bf16, [node][col] stride 136
  __shared__ __align__(16) unsigned short u_lds[128*36];
  __shared__ float rcS[32][3];
  __shared__ int degS[32];

  int tid = threadIdx.x;
  int bid = xcd_swz(blockIdx.x, NBLK_NL + NBLK_NP);
  int g = (bid < NBLK_NL) ? 0 : 1;
  int nb0 = (g ? bid - NBLK_NL : bid) * 32;
  int N = g ? NPOC : NLIG;
  float* h = g ? h_p : h_l;
  unsigned short* hbm = g ? hb_p : hb_l;
  float* x = g ? x_p : x_l;
  const unsigned short* m2e = g ? m2e_p : m2e_l;
  const float* relcf = g ? relcf_p : relcf_l;
  const int* offs = g ? offs_p : offs_l;
  int gl = g*NLAYERS + layer;
  const unsigned short* Wh1p = Wh1pb + (size_t)gl*G1S;
  const unsigned short* Wh2p = Wh2pb + (size_t)gl*G2S;
  const float* bh1 = bh1b + (size_t)gl*H;
  const float* bh2 = bh2b + (size_t)gl*H;

  int lane = tid & 63, wave = tid >> 6;

  // ---- phase A: CSR reduce; wave w owns nodes [w*16, w*16+16) (wave-private) ----
  {
    int nloc = tid >> 2, cb = (tid & 3) * 32;   // wave0 -> nloc 0..15, wave1 -> 16..31
    int gn = nb0 + nloc;
    int gna = (gn < N) ? gn : (N-1);
    int o0 = offs[gna], o1 = offs[gna+1];
    float sums[32];
    #pragma unroll
    for (int k=0;k<32;k++) sums[k] = 0.f;
    float rc0=0.f, rc1=0.f, rc2=0.f;
    bool rc_owner = (tid & 3) == 0;
    for (int e = o0; e < o1; e++){
      const unsigned short* mp = m2e + (size_t)e*H + cb;
      #pragma unroll
      for (int s2=0; s2<4; s2++){
        s8 v = *(const s8*)(mp + s2*8);
        #pragma unroll
        for (int j=0;j<8;j++)
          sums[s2*8+j] += bf2f((unsigned short)v[j]);
      }
      if (rc_owner){
        const float* rp = relcf + (size_t)e*3;
        rc0 += rp[0]; rc1 += rp[1]; rc2 += rp[2];
      }
    }
    unsigned short* ap = &aggS[nloc*136 + cb];
    #pragma unroll
    for (int s2=0; s2<4; s2++){
      s8 vv;
      #pragma unroll
      for (int j=0;j<8;j++) vv[j] = (short)f2bf(sums[s2*8+j]);
      *(s8*)(ap + s2*8) = vv;
    }
    if (rc_owner){
      rcS[nloc][0] = rc0; rcS[nloc][1] = rc1; rcS[nloc][2] = rc2;
      degS[nloc] = o1 - o0;
    }
  }

  // x update: wave-aligned (wave w -> its own nodes), no barrier needed
  if (lane < 48){
    int nn = wave*16 + lane/3, cc = lane - (lane/3)*3;
    int gn = nb0 + nn;
    if (gn < N){
      float dv = (float)degS[nn]; if (dv < 1.f) dv = 1.f;
      x[(size_t)gn*3 + cc] += rcS[nn][cc] / dv;
    }
  }

  int c = lane & 15, q = lane >> 4;
  int node = nb0 + wave*16 + c;
  int na = node < N ? node : N-1;
  int nloc2 = wave*16 + c;

  // A frags: ks 0..3 = h (bf16 mirror), ks 4..7 = aggS (bf16, wave-private rows)
  s8 af[8];
  #pragma unroll
  for (int ks=0; ks<4; ks++)
    af[ks] = *(const s8*)(hbm + (size_t)na*H + ks*32 + q*8);
  #pragma unroll
  for (int ks=4; ks<8; ks++)
    af[ks] = *(const s8*)&aggS[nloc2*136 + (ks-4)*32 + q*8];

  f32x4 acc[8];
  #pragma unroll
  for (int t=0;t<8;t++) acc[t] = (f32x4){0.f,0.f,0.f,0.f};
  const s8* B1 = (const s8*)Wh1p;
  #pragma unroll
  for (int ks=0; ks<8; ks++){
    const s8* bp = B1 + (ks*8)*64 + lane;
    #pragma unroll
    for (int t=0;t<8;t++)
      acc[t] = __builtin_amdgcn_mfma_f32_16x16x32_bf16(af[ks], bp[t*64], acc[t], 0,0,0);
  }

  int er0 = wave*16 + 4*q;
  #pragma unroll
  for (int t=0;t<8;t++){
    int j2 = 16*t + c;
    float b1 = bh1[j2];
    s4 mv;
    #pragma unroll
    for (int i=0;i<4;i++) mv[i] = (short)f2bf(silu_f(acc[t][i] + b1));
    *(s4*)&u_lds[36*j2 + er0] = mv;   // wave-private rows
  }

  f32x4 acc2[8];
  #pragma unroll
  for (int t=0;t<8;t++) acc2[t] = (f32x4){0.f,0.f,0.f,0.f};
  const s8* B2 = (const s8*)Wh2p;
  #pragma unroll
  for (int ks=0; ks<4; ks++){
    s8 a2;
    int base = 36*(32*ks + 8*q) + wave*16 + c;
    #pragma unroll
    for (int j=0;j<8;j++) a2[j] = (short)u_lds[base + 36*j];
    const s8* bp = B2 + (ks*8)*64 + lane;
    #pragma unroll
    for (int t=0;t<8;t++)
      acc2[t] = __builtin_amdgcn_mfma_f32_16x16x32_bf16(a2, bp[t*64], acc2[t], 0,0,0);
  }

  #pragma unroll
  for (int t=0;t<8;t++){
    int j2 = 16*t + c;
    float b2 = bh2[j2];
    #pragma unroll
    for (int i=0;i<4;i++){
      int gr = nb0 + wave*16 + 4*q + i;
      if (gr < N){
        size_t off = (size_t)gr*H + j2;
        float hv = h[off] + acc2[t][i] + b2;
        h[off] = hv;
        hbm[off] = f2bf(hv);
      }
    }
  }
}

// ---------------- NextType head via bf16 MFMA, 8 waves, f-parallel ----------------
__global__ __launch_bounds__(512, 2) void k_head3(
    const unsigned short* __restrict__ hb, const int* __restrict__ batch,
    const unsigned short* __restrict__ W1p, const float* __restrict__ bd1,
    const unsigned short* __restrict__ Wd2p, const float* __restrict__ bd2,
    const float* __restrict__ Wd3, const float* __restrict__ bd3,
    float* __restrict__ agg, int N)
{
  __shared__ __align__(16) unsigned short t1tr[96*132];
  __shared__ float t3s[32][18];
  __shared__ float lgs[32][18];
  __shared__ int bI[32];

  int tid = threadIdx.x;
  int nb0 = blockIdx.x * 32;
  int lane = tid & 63, wave = tid >> 6;
  int pair = wave >> 1, sub = wave & 1;
  int c = lane & 15, q = lane >> 4;

  int node = nb0 + sub*16 + c;
  int na = node < N ? node : N-1;

  s8 ah[4];
  #pragma unroll
  for (int ks=0; ks<4; ks++)
    ah[ks] = *(const s8*)(hb + (size_t)na*H + ks*32 + q*8);

  float b1c[6];
  #pragma unroll
  for (int t=0;t<6;t++){ int col=16*t+c; b1c[t] = (col<85) ? bd1[col] : 0.f; }
  float b2c[3], w3c[3];
  #pragma unroll
  for (int t=0;t<3;t++){
    int col=16*t+c;
    b2c[t] = (col<43) ? bd2[col] : 0.f;
    w3c[t] = (col<43) ? Wd3[col] : 0.f;
  }
  float bd3v = bd3[0];
  int rbase = wave*16;
  int er0 = rbase + 4*q;

  for (int fi=0; fi<4; fi++){
    int f = pair + 4*fi;
    const s8* B1 = (const s8*)W1p + f*(W1FS/8);
    f32x4 acc[6];
    #pragma unroll
    for (int t=0;t<6;t++) acc[t] = (f32x4){0.f,0.f,0.f,0.f};
    #pragma unroll
    for (int ks=0; ks<4; ks++){
      #pragma unroll
      for (int t=0;t<6;t++)
        acc[t] = __builtin_amdgcn_mfma_f32_16x16x32_bf16(ah[ks], B1[(ks*6+t)*64+lane], acc[t], 0,0,0);
    }
    #pragma unroll
    for (int t=0;t<6;t++){
      int j2 = 16*t + c;
      s4 mv;
      #pragma unroll
      for (int i=0;i<4;i++) mv[i] = (short)f2bf(silu_f(acc[t][i] + b1c[t]));
      *(s4*)&t1tr[132*j2 + er0] = mv;
    }
    f32x4 acc2[3];
    #pragma unroll
    for (int t=0;t<3;t++) acc2[t] = (f32x4){0.f,0.f,0.f,0.f};
    const s8* B2 = (const s8*)Wd2p;
    #pragma unroll
    for (int ks=0; ks<3; ks++){
      s8 a2;
      int base = 132*(32*ks + 8*q) + rbase + c;
      #pragma unroll
      for (int j=0;j<8;j++) a2[j] = (short)t1tr[base + 132*j];
      #pragma unroll
      for (int t=0;t<3;t++)
        acc2[t] = __builtin_amdgcn_mfma_f32_16x16x32_bf16(a2, B2[(ks*3+t)*64+lane], acc2[t], 0,0,0);
    }
    float pp[4] = {0.f,0.f,0.f,0.f};
    #pragma unroll
    for (int t=0;t<3;t++){
      #pragma unroll
      for (int i=0;i<4;i++) pp[i] += silu_f(acc2[t][i] + b2c[t]) * w3c[t];
    }
    #pragma unroll
    for (int off=1; off<16; off<<=1){
      #pragma unroll
      for (int i=0;i<4;i++) pp[i] += __shfl_xor(pp[i], off, 64);
    }
    if (c == 0){
      #pragma unroll
      for (int i=0;i<4;i++) t3s[sub*16 + 4*q + i][f] = pp[i] + bd3v;
    }
  }
  __syncthreads();

  if (tid < 32){
    int n = nb0 + tid;
    bool valid = n < N;
    bI[tid] = batch[valid ? n : (N-1)];
    if (valid){
      float m = t3s[tid][0];
      #pragma unroll
      for (int i=1;i<16;i++) m = fmaxf(m, t3s[tid][i]);
      float s = 0.f;
      #pragma unroll
      for (int i=0;i<16;i++) s += __expf(t3s[tid][i] - m);
      float ls = __logf(s);
      #pragma unroll
      for (int i=0;i<16;i++) lgs[tid][i] = t3s[tid][i] - m - ls;
    } else {
      #pragma unroll
      for (int i=0;i<16;i++) lgs[tid][i] = 0.f;
    }
  }
  __syncthreads();

  if (tid < 16){
    int f = tid;
    float acc = 0.f; int run = bI[0];
    for (int n = 0; n < 32; n++){
      int b = bI[n];
      if (b != run){ atomicAdd(&agg[run*16 + f], acc); acc = 0.f; run = b; }
      acc += lgs[n][f];
    }
    atomicAdd(&agg[run*16 + f], acc);
  }
}

// ---------------- final: out = agg - logsumexp(agg) ----------------
__global__ void k_final(const float* __restrict__ agg, float* __restrict__ out){
  int tid = threadIdx.x;
  float vv = agg[tid];
  float m = vv;
  #pragma unroll
  for (int off = 1; off < 16; off <<= 1) m = fmaxf(m, __shfl_xor(m, off, 64));
  float s = __expf(vv - m);
  #pragma unroll
  for (int off = 1; off < 16; off <<= 1) s += __shfl_xor(s, off, 64);
  out[tid] = vv - m - __logf(s);
}

extern "C" void kernel_launch(void* const* d_in, const int* in_sizes, int n_in,
                              void* d_out, int out_size, void* d_ws, size_t ws_size,
                              hipStream_t stream)
{
  const float* ligand_x   = (const float*)d_in[0];
  const float* pocket_x   = (const float*)d_in[1];
  const float* ligand_pos = (const float*)d_in[2];
  const float* pocket_pos = (const float*)d_in[3];
  const float* Wl_emb = (const float*)d_in[4];
  const float* bl_emb = (const float*)d_in[5];
  const float* Wp_emb = (const float*)d_in[6];
  const float* bp_emb = (const float*)d_in[7];
  const float* We1 = (const float*)d_in[8];
  const float* be1 = (const float*)d_in[9];
  const float* We2 = (const float*)d_in[10];
  const float* be2 = (const float*)d_in[11];
  const float* Wx  = (const float*)d_in[12];
  const float* bx  = (const float*)d_in[13];
  const float* Wh1 = (const float*)d_in[14];
  const float* bh1 = (const float*)d_in[15];
  const float* Wh2 = (const float*)d_in[16];
  const float* bh2 = (const float*)d_in[17];
  const float* Wd1 = (const float*)d_in[18];
  const float* bd1 = (const float*)d_in[19];
  const float* Wd2 = (const float*)d_in[20];
  const float* bd2 = (const float*)d_in[21];
  const float* Wd3 = (const float*)d_in[22];
  const float* bd3 = (const float*)d_in[23];
  const int* l2l    = (const int*)d_in[24];
  const int* p2p    = (const int*)d_in[25];
  const int* lbatch = (const int*)d_in[26];

  char* w = (char*)d_ws;
  auto alloc = [&](size_t bytes)->char*{
    char* p = w; w += (bytes + 255) & ~(size_t)255; return p;
  };
  float* hl    = (float*)alloc((size_t)NLIG*H*4);
  float* hp    = (float*)alloc((size_t)NPOC*H*4);
  unsigned short* hbl = (unsigned short*)alloc((size_t)NLIG*H*2);
  unsigned short* hbp = (unsigned short*)alloc((size_t)NPOC*H*2);
  float* xl    = (float*)alloc((size_t)NLIG*3*4);
  float* xp    = (float*)alloc((size_t)NPOC*3*4);
  int* offs_l = (int*)alloc((size_t)(NLIG+1)*4);
  int* offs_p = (int*)alloc((size_t)(NPOC+1)*4);
  int* ssrc_l = (int*)alloc((size_t)ELIG*4);
  int* sdst_l = (int*)alloc((size_t)ELIG*4);
  int* ssrc_p = (int*)alloc((size_t)EPOC*4);
  int* sdst_p = (int*)alloc((size_t)EPOC*4);
  unsigned short* We1p = (unsigned short*)alloc((size_t)6*G1S*2);
  unsigned short* We2p = (unsigned short*)alloc((size_t)6*G2S*2);
  unsigned short* Wh1p = (unsigned short*)alloc((size_t)6*G1S*2);
  unsigned short* Wh2p = (unsigned short*)alloc((size_t)6*G2S*2);
  unsigned short* W1p  = (unsigned short*)alloc((size_t)16*W1FS*2);
  unsigned short* Wd2p = (unsigned short*)alloc((size_t)WD2S*2);
  unsigned short* m2e_l = (unsigned short*)alloc((size_t)ELIG*H*2);
  unsigned short* m2e_p = (unsigned short*)alloc((size_t)EPOC*H*2);
  float* relcf_l = (float*)alloc((size_t)ELIG*3*4);
  float* relcf_p = (float*)alloc((size_t)EPOC*3*4);
  // ---- contiguous zero-init region ----
  char* zbase = w;
  int* deg_l = (int*)alloc((size_t)NLIG*4);
  int* deg_p = (int*)alloc((size_t)NPOC*4);
  int* cur_l = (int*)alloc((size_t)NLIG*4);
  int* cur_p = (int*)alloc((size_t)NPOC*4);
  float* aggB = (float*)alloc((size_t)NB*16*4);
  size_t zsize = (size_t)(w - zbase);

  hipMemsetAsync(zbase, 0, zsize, stream);

  const int* lsrc = l2l;          const int* ldst = l2l + ELIG;
  const int* psrc = p2p;          const int* pdst = p2p + EPOC;

  k_embed2<<<NLIG/2 + NPOC/2, 256, 0, stream>>>(ligand_x, pocket_x, ligand_pos, pocket_pos,
      Wl_emb, bl_emb, Wp_emb, bp_emb, hl, hbl, hp, hbp, xl, xp);
  k_hist2<<<(ELIG+EPOC+255)/256, 256, 0, stream>>>(ldst, pdst, deg_l, deg_p);
  k_scan2<<<2, 1024, 0, stream>>>(deg_l, offs_l, deg_p, offs_p);
  k_sort2<<<(ELIG+EPOC+255)/256, 256, 0, stream>>>(lsrc, ldst, psrc, pdst,
      offs_l, offs_p, cur_l, cur_p, ssrc_l, sdst_l, ssrc_p, sdst_p);
  {
    int npack = 6*G1S + 6*G2S + 6*G1S + 6*G2S + 16*W1FS + WD2S;
    k_pack<<<(npack+255)/256, 256, 0, stream>>>(We1, We2, Wh1, Wh2,
        Wl_emb, bl_emb, Wd1, Wd2, We1p, We2p, Wh1p, Wh2p, W1p, Wd2p);
  }

  for (int l = 0; l < NLAYERS; l++){
    k_edge_f<<<NBLK_EL + NBLK_EP, 256, 0, stream>>>(hbl, hbp, xl, xp,
        ssrc_l, sdst_l, ssrc_p, sdst_p,
        We1p, We1, be1, We2p, be2, Wx, bx,
        m2e_l, relcf_l, m2e_p, relcf_p, l);
    k_node_f<<<NBLK_NL + NBLK_NP, 128, 0, stream>>>(hl, hbl, xl, hp, hbp, xp,
        m2e_l, relcf_l, m2e_p, relcf_p, offs_l, offs_p,
        Wh1p, bh1, Wh2p, bh2, l);
  }

  k_head3<<<(NLIG+31)/32, 512, 0, stream>>>(hbl, lbatch, W1p, bd1, Wd2p, bd2,
                                            Wd3, bd3, aggB, NLIG);
  k_final<<<1, 128, 0, stream>>>(aggB, (float*)d_out);
}